// Round 4
// baseline (1253.395 us; speedup 1.0000x reference)
//
#include <hip/hip_runtime.h>
#include <hip/hip_bf16.h>

#define NAT 4096
#define NXQ 8192
#define DIM 128
#define KNN 16
#define HD  257   // 2*DIM+1
#define NLAYER 3
#define SLOPE 0.2f
#define GN_EPS 1e-5f
#define APB 2     // atoms per block in mp_layer
#define BIGD 1e30f

__device__ __forceinline__ float leakyf(float z) { return z >= 0.0f ? z : SLOPE * z; }

// ---------------- fill ----------------
__global__ void fill_f32_r4(float* __restrict__ p, int n, float v)
{
    int i = blockIdx.x * 256 + threadIdx.x;
    if (i < n) p[i] = v;
}

// ---------------- initial per-atom feature MLP ----------------
__global__ __launch_bounds__(128) void feat_transform_r4(
    const float* __restrict__ af,
    const float* __restrict__ tw1, const float* __restrict__ tb1,
    const float* __restrict__ tw2, const float* __restrict__ tb2,
    float* __restrict__ out)
{
    const int i = blockIdx.x;
    const int t = threadIdx.x;
    __shared__ __align__(16) float a_s[DIM];
    __shared__ __align__(16) float h_s[DIM];
    a_s[t] = af[i * DIM + t];
    __syncthreads();
    float acc = tb1[t];
    #pragma unroll 2
    for (int k = 0; k < DIM; k += 4) {
        float4 v = *(const float4*)&a_s[k];
        acc = fmaf(v.x, tw1[(k + 0) * DIM + t], acc);
        acc = fmaf(v.y, tw1[(k + 1) * DIM + t], acc);
        acc = fmaf(v.z, tw1[(k + 2) * DIM + t], acc);
        acc = fmaf(v.w, tw1[(k + 3) * DIM + t], acc);
    }
    h_s[t] = leakyf(acc);
    __syncthreads();
    float acc2 = tb2[t];
    #pragma unroll 2
    for (int k = 0; k < DIM; k += 4) {
        float4 v = *(const float4*)&h_s[k];
        acc2 = fmaf(v.x, tw2[(k + 0) * DIM + t], acc2);
        acc2 = fmaf(v.y, tw2[(k + 1) * DIM + t], acc2);
        acc2 = fmaf(v.z, tw2[(k + 2) * DIM + t], acc2);
        acc2 = fmaf(v.w, tw2[(k + 3) * DIM + t], acc2);
    }
    out[i * DIM + t] = acc2;
}

// ---------------- KNN (atom->atom excl self, and xyz->atom) ----------------
__device__ __forceinline__ int lbound_r4(const int* __restrict__ arr, int n, int v)
{
    int lo = 0, hi = n;
    while (lo < hi) { int m = (lo + hi) >> 1; if (arr[m] < v) lo = m + 1; else hi = m; }
    return lo;
}

__global__ __launch_bounds__(256) void knn_r4(
    const float* __restrict__ xyz, const int* __restrict__ xbatch,
    const float* __restrict__ axyz, const int* __restrict__ abatch,
    int* __restrict__ idx_aa, float* __restrict__ dist_aa,
    int* __restrict__ idx_xa, float* __restrict__ dist_xa)
{
    int tid = blockIdx.x * blockDim.x + threadIdx.x;
    if (tid >= NAT + NXQ) return;
    const bool is_aa = tid < NAT;
    const int q = is_aa ? tid : tid - NAT;
    float qx, qy, qz; int qb;
    if (is_aa) { qx = axyz[3 * q]; qy = axyz[3 * q + 1]; qz = axyz[3 * q + 2]; qb = abatch[q]; }
    else       { qx = xyz[3 * q];  qy = xyz[3 * q + 1];  qz = xyz[3 * q + 2];  qb = xbatch[q]; }
    const int lo = lbound_r4(abatch, NAT, qb);
    const int hi = lbound_r4(abatch, NAT, qb + 1);
    const int self = is_aa ? q : -1;

    float ad[KNN]; int ai[KNN];
    #pragma unroll
    for (int s = 0; s < KNN; ++s) { ad[s] = BIGD; ai[s] = 0; }

    for (int j = lo; j < hi; ++j) {
        float dx = qx - axyz[3 * j];
        float dy = qy - axyz[3 * j + 1];
        float dz = qz - axyz[3 * j + 2];
        float d2 = dx * dx + dy * dy + dz * dz;
        if (j == self) d2 = BIGD;
        // branchless sorted insert; strict < keeps earlier index on ties
        float cd = d2; int ci = j;
        #pragma unroll
        for (int s = 0; s < KNN; ++s) {
            bool ins = cd < ad[s];
            float nd = ins ? cd : ad[s];
            int   ni = ins ? ci : ai[s];
            float od = ins ? ad[s] : cd;
            int   oi = ins ? ai[s] : ci;
            ad[s] = nd; ai[s] = ni; cd = od; ci = oi;
        }
    }
    int*   ip = is_aa ? (idx_aa + q * KNN)  : (idx_xa + q * KNN);
    float* dp = is_aa ? (dist_aa + q * KNN) : (dist_xa + q * KNN);
    #pragma unroll
    for (int s = 0; s < KNN; ++s) { ip[s] = ai[s]; dp[s] = ad[s]; }
}

// ---------------- message-passing layer (f32 out) ----------------
// dst[i] = center[i] + leaky(GN( (sum_e leaky([cen,nbr,dist]@w1+b1)) @ w2 + 16*b2 ))
// In-place (dst == centers) is safe: a block reads only its own center rows
// before its own writes; src must then be a different buffer.
__global__ __launch_bounds__(256) void mp_layer_r4(
    const float* __restrict__ centers,
    const float* __restrict__ src,
    const int*   __restrict__ nidx,
    const float* __restrict__ ndist,
    const float* __restrict__ w1, const float* __restrict__ b1,
    const float* __restrict__ w2, const float* __restrict__ b2,
    const float* __restrict__ gw, const float* __restrict__ gb,
    float* __restrict__ dst)
{
    const int t = threadIdx.x;
    const int i0 = blockIdx.x * APB;

    __shared__ __align__(16) float cen_s[APB][DIM];
    __shared__ __align__(16) float nbr_s[APB][KNN][DIM];
    __shared__ __align__(16) float sd_s[APB][KNN];
    __shared__ __align__(16) float S_s[APB][260];   // 257 used
    __shared__ __align__(16) float h256_s[APB][KNN];
    __shared__ __align__(16) float c1_256_s[4];

    // ---- stage A: stage centers, neighbor rows, dists into LDS ----
    {
        int a = t >> 7, j = t & 127;
        cen_s[a][j] = centers[(i0 + a) * DIM + j];
    }
    if (t < APB * KNN) {
        int a = t >> 4, e = t & 15;
        sd_s[a][e] = ndist[(i0 + a) * KNN + e];
    }
    #pragma unroll
    for (int it = 0; it < 4; ++it) {
        int lin = it * 256 + t;              // 0..1023 float4 slots
        int a = lin >> 9, e = (lin >> 5) & 15, qd = lin & 31;
        int row = nidx[(i0 + a) * KNN + e];
        *(float4*)&nbr_s[a][e][qd * 4] = *(const float4*)&src[row * DIM + qd * 4];
    }
    __syncthreads();

    // ---- stage B: c1[j] = b1[j] + center @ w1[0:128, j] (shared by all 16 edges) ----
    float c1r0, c1r1;
    {
        float acc0 = b1[t], acc1 = b1[t];
        #pragma unroll 2
        for (int k = 0; k < DIM; k += 4) {
            float w0 = w1[(k + 0) * HD + t];
            float wa = w1[(k + 1) * HD + t];
            float wb = w1[(k + 2) * HD + t];
            float wc = w1[(k + 3) * HD + t];
            float4 c0 = *(const float4*)&cen_s[0][k];
            float4 c1v = *(const float4*)&cen_s[1][k];
            acc0 = fmaf(c0.x, w0, acc0);  acc0 = fmaf(c0.y, wa, acc0);
            acc0 = fmaf(c0.z, wb, acc0);  acc0 = fmaf(c0.w, wc, acc0);
            acc1 = fmaf(c1v.x, w0, acc1); acc1 = fmaf(c1v.y, wa, acc1);
            acc1 = fmaf(c1v.z, wb, acc1); acc1 = fmaf(c1v.w, wc, acc1);
        }
        c1r0 = acc0; c1r1 = acc1;
    }
    // c1 column 256 (wave 0 -> atom 0, wave 1 -> atom 1)
    if (t < 128) {
        int a = t >> 6, l = t & 63;
        float p = cen_s[a][l] * w1[l * HD + 256]
                + cen_s[a][l + 64] * w1[(l + 64) * HD + 256];
        #pragma unroll
        for (int m = 1; m < 64; m <<= 1) p += __shfl_xor(p, m);
        if (l == 0) c1_256_s[a] = p + b1[256];
    }
    __syncthreads();

    // ---- stage C: per-edge hidden col j=t, both atoms; S = sum_e leaky(h1) ----
    {
        const float w1r256 = w1[256 * HD + t];
        float Ssum0 = 0.0f, Ssum1 = 0.0f;

        #pragma unroll 1
        for (int ec = 0; ec < 2; ++ec) {           // 8 edges per chunk
            float acc[APB][8];
            #pragma unroll
            for (int u = 0; u < 8; ++u) {
                acc[0][u] = fmaf(sd_s[0][ec * 8 + u], w1r256, c1r0);
                acc[1][u] = fmaf(sd_s[1][ec * 8 + u], w1r256, c1r1);
            }

            #pragma unroll 2
            for (int k = 0; k < DIM; k += 4) {
                float w0 = w1[(128 + k + 0) * HD + t];
                float wa = w1[(128 + k + 1) * HD + t];
                float wb = w1[(128 + k + 2) * HD + t];
                float wc = w1[(128 + k + 3) * HD + t];
                #pragma unroll
                for (int a = 0; a < APB; ++a) {
                    #pragma unroll
                    for (int u = 0; u < 8; ++u) {
                        float4 f = *(const float4*)&nbr_s[a][ec * 8 + u][k];
                        acc[a][u] = fmaf(f.x, w0, acc[a][u]);
                        acc[a][u] = fmaf(f.y, wa, acc[a][u]);
                        acc[a][u] = fmaf(f.z, wb, acc[a][u]);
                        acc[a][u] = fmaf(f.w, wc, acc[a][u]);
                    }
                }
            }
            #pragma unroll
            for (int u = 0; u < 8; ++u) {
                Ssum0 += leakyf(acc[0][u]);
                Ssum1 += leakyf(acc[1][u]);
            }
        }
        S_s[0][t] = Ssum0;
        S_s[1][t] = Ssum1;
    }
    // stage C, hidden column 256: 16 lanes per edge, both atoms
    {
        int e = t >> 4, kk = t & 15;
        float p0 = 0.0f, p1 = 0.0f;
        #pragma unroll
        for (int m = 0; m < 8; ++m) {
            int k = kk + 16 * m;
            float wc = w1[(128 + k) * HD + 256];
            p0 = fmaf(nbr_s[0][e][k], wc, p0);
            p1 = fmaf(nbr_s[1][e][k], wc, p1);
        }
        #pragma unroll
        for (int m = 1; m < 16; m <<= 1) {
            p0 += __shfl_xor(p0, m);
            p1 += __shfl_xor(p1, m);
        }
        if (kk == 0) {
            float wt = w1[256 * HD + 256];
            h256_s[0][e] = leakyf(c1_256_s[0] + sd_s[0][e] * wt + p0);
            h256_s[1][e] = leakyf(c1_256_s[1] + sd_s[1][e] * wt + p1);
        }
    }
    __syncthreads();
    if (t < APB) {
        float s = 0.0f;
        #pragma unroll
        for (int e = 0; e < KNN; ++e) s += h256_s[t][e];
        S_s[t][256] = s;
    }
    __syncthreads();

    // ---- stage D: msg[j] = 16*b2[j] + S @ w2[:, j]; GroupNorm + residual ----
    const int a = t >> 7, j = t & 127;
    float macc = 16.0f * b2[j];
    #pragma unroll 2
    for (int k = 0; k < 256; k += 4) {
        float4 sv = *(const float4*)&S_s[a][k];
        macc = fmaf(sv.x, w2[(k + 0) * DIM + j], macc);
        macc = fmaf(sv.y, w2[(k + 1) * DIM + j], macc);
        macc = fmaf(sv.z, w2[(k + 2) * DIM + j], macc);
        macc = fmaf(sv.w, w2[(k + 3) * DIM + j], macc);
    }
    macc = fmaf(S_s[a][256], w2[256 * DIM + j], macc);

    // GroupNorm(groups=2): each wave is exactly one (atom, 64-channel group)
    float s = macc;
    #pragma unroll
    for (int m = 1; m < 64; m <<= 1) s += __shfl_xor(s, m);
    float mu = s * (1.0f / 64.0f);
    float d = macc - mu;
    float ss = d * d;
    #pragma unroll
    for (int m = 1; m < 64; m <<= 1) ss += __shfl_xor(ss, m);
    float var = ss * (1.0f / 64.0f);
    float xn = d * rsqrtf(var + GN_EPS);
    float y = fmaf(xn, gw[j], gb[j]);
    dst[(i0 + a) * DIM + j] = cen_s[a][j] + leakyf(y);
}

extern "C" void kernel_launch(void* const* d_in, const int* in_sizes, int n_in,
                              void* d_out, int out_size, void* d_ws, size_t ws_size,
                              hipStream_t stream)
{
    const size_t out_bytes = (size_t)out_size * sizeof(float);   // f32 output

    // Diagnostic: input-count mismatch -> d_out bytes 0x43 (f32 ~193.3)
    if (n_in != 21) {
        (void)hipMemsetAsync(d_out, 0x43, out_bytes, stream);
        return;
    }
    // Workspace layout (floats): atoms_a, atoms_b, emb, idx_aa, dist_aa, idx_xa, dist_xa
    const size_t need_elems = (size_t)NAT * DIM * 2 + (size_t)NXQ * DIM
                            + (size_t)NAT * KNN * 2 + (size_t)NXQ * KNN * 2;
    // Diagnostic: workspace too small -> d_out bytes 0x41 (f32 ~12.08)
    if (ws_size < need_elems * sizeof(float)) {
        (void)hipMemsetAsync(d_out, 0x41, out_bytes, stream);
        return;
    }

    const float* xyz    = (const float*)d_in[0];
    const float* axyz   = (const float*)d_in[1];
    const float* af     = (const float*)d_in[2];
    const int*   xbatch = (const int*)d_in[3];
    const int*   abatch = (const int*)d_in[4];
    const float* tw1    = (const float*)d_in[5];
    const float* tb1    = (const float*)d_in[6];
    const float* tw2    = (const float*)d_in[7];
    const float* tb2    = (const float*)d_in[8];
    const float* aa_w1  = (const float*)d_in[9];
    const float* aa_b1  = (const float*)d_in[10];
    const float* aa_w2  = (const float*)d_in[11];
    const float* aa_b2  = (const float*)d_in[12];
    const float* aa_gw  = (const float*)d_in[13];
    const float* aa_gb  = (const float*)d_in[14];
    const float* ae_w1  = (const float*)d_in[15];
    const float* ae_b1  = (const float*)d_in[16];
    const float* ae_w2  = (const float*)d_in[17];
    const float* ae_b2  = (const float*)d_in[18];
    const float* ae_gw  = (const float*)d_in[19];
    const float* ae_gb  = (const float*)d_in[20];

    float* ws      = (float*)d_ws;
    float* atoms_a = ws;
    float* atoms_b = atoms_a + (size_t)NAT * DIM;
    float* emb     = atoms_b + (size_t)NAT * DIM;
    int*   idx_aa  = (int*)(emb + (size_t)NXQ * DIM);
    float* dist_aa = (float*)(idx_aa + (size_t)NAT * KNN);
    int*   idx_xa  = (int*)(dist_aa + (size_t)NAT * KNN);
    float* dist_xa = (float*)(idx_xa + (size_t)NXQ * KNN);

    const int NOUT = NXQ * DIM;

    // emb <- 1.0f (reference's jnp.ones initial embedding)
    fill_f32_r4<<<(NOUT + 255) / 256, 256, 0, stream>>>(emb, NOUT, 1.0f);

    feat_transform_r4<<<NAT, 128, 0, stream>>>(af, tw1, tb1, tw2, tb2, atoms_a);
    knn_r4<<<(NAT + NXQ + 255) / 256, 256, 0, stream>>>(
        xyz, xbatch, axyz, abatch, idx_aa, dist_aa, idx_xa, dist_xa);

    // atom-atom layers: a -> b -> a -> b
    float* cur = atoms_a;
    float* nxt = atoms_b;
    for (int i = 0; i < NLAYER; ++i) {
        mp_layer_r4<<<NAT / APB, 256, 0, stream>>>(
            cur, cur, idx_aa, dist_aa,
            aa_w1 + (size_t)i * HD * HD, aa_b1 + (size_t)i * HD,
            aa_w2 + (size_t)i * HD * DIM, aa_b2 + (size_t)i * DIM,
            aa_gw + (size_t)i * DIM, aa_gb + (size_t)i * DIM, nxt);
        float* tmp = cur; cur = nxt; nxt = tmp;
    }
    const float* atoms_final = cur;

    // xyz-atom layers: layers 0,1 update emb in place (src = atoms buffer, no alias
    // hazard); final layer writes f32 directly into d_out.
    for (int i = 0; i < NLAYER; ++i) {
        float* dsti = (i == NLAYER - 1) ? (float*)d_out : emb;
        mp_layer_r4<<<NXQ / APB, 256, 0, stream>>>(
            emb, atoms_final, idx_xa, dist_xa,
            ae_w1 + (size_t)i * HD * HD, ae_b1 + (size_t)i * HD,
            ae_w2 + (size_t)i * HD * DIM, ae_b2 + (size_t)i * DIM,
            ae_gw + (size_t)i * DIM, ae_gb + (size_t)i * DIM, dsti);
    }
}

// Round 5
// 967.705 us; speedup vs baseline: 1.2952x; 1.2952x over previous
//
#include <hip/hip_runtime.h>
#include <hip/hip_bf16.h>

#define NAT 4096
#define NXQ 8192
#define DIM 128
#define KNN 16
#define HD  257   // 2*DIM+1
#define NLAYER 3
#define SLOPE 0.2f
#define GN_EPS 1e-5f
#define BIGD 1e30f

typedef __attribute__((ext_vector_type(8))) short short8v;   // 8 bf16 = 4 VGPR
typedef __attribute__((ext_vector_type(4))) float f32x4;

__device__ __forceinline__ float leakyf(float z) { return z >= 0.0f ? z : SLOPE * z; }
__device__ __forceinline__ unsigned short bf16_rn(float x) {
    unsigned u = __float_as_uint(x);
    unsigned r = (u + 0x7FFFu + ((u >> 16) & 1u)) >> 16;
    return (unsigned short)r;
}
__device__ __forceinline__ float bf16f(unsigned short h) {
    return __uint_as_float(((unsigned)h) << 16);
}

// ---------------- fill ----------------
__global__ void fill_f32_r5(float* __restrict__ p, int n, float v)
{
    int i = blockIdx.x * 256 + threadIdx.x;
    if (i < n) p[i] = v;
}

// ---------------- bf16 split: x = hi + lo ----------------
__global__ void split_bf16_r5(const float* __restrict__ x,
                              unsigned short* __restrict__ hi,
                              unsigned short* __restrict__ lo, int n)
{
    int i = blockIdx.x * 256 + threadIdx.x;
    if (i < n) {
        float v = x[i];
        unsigned short h = bf16_rn(v);
        hi[i] = h;
        lo[i] = bf16_rn(v - bf16f(h));
    }
}

// ---------------- pack W1b (rows 128..255, cols 0..255) into MFMA B-fragment order ----
// fragment (ct, ks): lane l, slot s holds W1[128 + ks*32 + (l>>4)*8 + s][ct*16 + (l&15)]
__global__ __launch_bounds__(64) void pack_w1_r5(const float* __restrict__ w1,
                                                 unsigned short* __restrict__ bhi,
                                                 unsigned short* __restrict__ blo)
{
    const int blk = blockIdx.x;          // ct*4 + ks, 64 blocks
    const int l = threadIdx.x;
    const int col = (blk >> 2) * 16 + (l & 15);
    const int kbase = 128 + (blk & 3) * 32 + (l >> 4) * 8;
    unsigned short h8[8], l8[8];
    #pragma unroll
    for (int s = 0; s < 8; ++s) {
        float w = w1[(kbase + s) * HD + col];
        unsigned short h = bf16_rn(w);
        h8[s] = h;
        l8[s] = bf16_rn(w - bf16f(h));
    }
    const int off = (blk * 64 + l) * 8;
    #pragma unroll
    for (int s = 0; s < 8; ++s) { bhi[off + s] = h8[s]; blo[off + s] = l8[s]; }
}

// ---------------- initial per-atom feature MLP ----------------
__global__ __launch_bounds__(128) void feat_transform_r5(
    const float* __restrict__ af,
    const float* __restrict__ tw1, const float* __restrict__ tb1,
    const float* __restrict__ tw2, const float* __restrict__ tb2,
    float* __restrict__ out)
{
    const int i = blockIdx.x;
    const int t = threadIdx.x;
    __shared__ __align__(16) float a_s[DIM];
    __shared__ __align__(16) float h_s[DIM];
    a_s[t] = af[i * DIM + t];
    __syncthreads();
    float acc = tb1[t];
    #pragma unroll 2
    for (int k = 0; k < DIM; k += 4) {
        float4 v = *(const float4*)&a_s[k];
        acc = fmaf(v.x, tw1[(k + 0) * DIM + t], acc);
        acc = fmaf(v.y, tw1[(k + 1) * DIM + t], acc);
        acc = fmaf(v.z, tw1[(k + 2) * DIM + t], acc);
        acc = fmaf(v.w, tw1[(k + 3) * DIM + t], acc);
    }
    h_s[t] = leakyf(acc);
    __syncthreads();
    float acc2 = tb2[t];
    #pragma unroll 2
    for (int k = 0; k < DIM; k += 4) {
        float4 v = *(const float4*)&h_s[k];
        acc2 = fmaf(v.x, tw2[(k + 0) * DIM + t], acc2);
        acc2 = fmaf(v.y, tw2[(k + 1) * DIM + t], acc2);
        acc2 = fmaf(v.z, tw2[(k + 2) * DIM + t], acc2);
        acc2 = fmaf(v.w, tw2[(k + 3) * DIM + t], acc2);
    }
    out[i * DIM + t] = acc2;
}

// ---------------- KNN ----------------
__device__ __forceinline__ int lbound_r5(const int* __restrict__ arr, int n, int v)
{
    int lo = 0, hi = n;
    while (lo < hi) { int m = (lo + hi) >> 1; if (arr[m] < v) lo = m + 1; else hi = m; }
    return lo;
}

__global__ __launch_bounds__(256) void knn_r5(
    const float* __restrict__ xyz, const int* __restrict__ xbatch,
    const float* __restrict__ axyz, const int* __restrict__ abatch,
    int* __restrict__ idx_aa, float* __restrict__ dist_aa,
    int* __restrict__ idx_xa, float* __restrict__ dist_xa)
{
    int tid = blockIdx.x * blockDim.x + threadIdx.x;
    if (tid >= NAT + NXQ) return;
    const bool is_aa = tid < NAT;
    const int q = is_aa ? tid : tid - NAT;
    float qx, qy, qz; int qb;
    if (is_aa) { qx = axyz[3 * q]; qy = axyz[3 * q + 1]; qz = axyz[3 * q + 2]; qb = abatch[q]; }
    else       { qx = xyz[3 * q];  qy = xyz[3 * q + 1];  qz = xyz[3 * q + 2];  qb = xbatch[q]; }
    const int lo = lbound_r5(abatch, NAT, qb);
    const int hi = lbound_r5(abatch, NAT, qb + 1);
    const int self = is_aa ? q : -1;

    float ad[KNN]; int ai[KNN];
    #pragma unroll
    for (int s = 0; s < KNN; ++s) { ad[s] = BIGD; ai[s] = 0; }

    for (int j = lo; j < hi; ++j) {
        float dx = qx - axyz[3 * j];
        float dy = qy - axyz[3 * j + 1];
        float dz = qz - axyz[3 * j + 2];
        float d2 = dx * dx + dy * dy + dz * dz;
        if (j == self) d2 = BIGD;
        if (d2 < ad[KNN - 1]) {       // mostly-false fast skip
            float cd = d2; int ci = j;
            #pragma unroll
            for (int s = 0; s < KNN; ++s) {
                bool ins = cd < ad[s];
                float nd = ins ? cd : ad[s];
                int   ni = ins ? ci : ai[s];
                float od = ins ? ad[s] : cd;
                int   oi = ins ? ai[s] : ci;
                ad[s] = nd; ai[s] = ni; cd = od; ci = oi;
            }
        }
    }
    int*   ip = is_aa ? (idx_aa + q * KNN)  : (idx_xa + q * KNN);
    float* dp = is_aa ? (dist_aa + q * KNN) : (dist_xa + q * KNN);
    #pragma unroll
    for (int s = 0; s < KNN; ++s) { ip[s] = ai[s]; dp[s] = ad[s]; }
}

// ---------------- c1 = b1 + center @ w1[0:128,:]  (cols 0..256) ----------------
__global__ __launch_bounds__(256) void c1_kernel_r5(
    const float* __restrict__ centers, const float* __restrict__ w1,
    const float* __restrict__ b1, float* __restrict__ c1ws)
{
    const int t = threadIdx.x;
    const int i0 = blockIdx.x * 2;
    __shared__ __align__(16) float cen_s[2][DIM];
    {
        int a = t >> 7, j = t & 127;
        cen_s[a][j] = centers[(i0 + a) * DIM + j];
    }
    __syncthreads();
    float acc0 = b1[t], acc1 = b1[t];
    #pragma unroll 2
    for (int k = 0; k < DIM; k += 4) {
        float w0 = w1[(k + 0) * HD + t];
        float wa = w1[(k + 1) * HD + t];
        float wb = w1[(k + 2) * HD + t];
        float wc = w1[(k + 3) * HD + t];
        float4 c0 = *(const float4*)&cen_s[0][k];
        float4 c1v = *(const float4*)&cen_s[1][k];
        acc0 = fmaf(c0.x, w0, acc0);  acc0 = fmaf(c0.y, wa, acc0);
        acc0 = fmaf(c0.z, wb, acc0);  acc0 = fmaf(c0.w, wc, acc0);
        acc1 = fmaf(c1v.x, w0, acc1); acc1 = fmaf(c1v.y, wa, acc1);
        acc1 = fmaf(c1v.z, wb, acc1); acc1 = fmaf(c1v.w, wc, acc1);
    }
    c1ws[(size_t)(i0 + 0) * HD + t] = acc0;
    c1ws[(size_t)(i0 + 1) * HD + t] = acc1;
    // column 256
    if (t < 128) {
        int a = t >> 6, l = t & 63;
        float p = cen_s[a][l] * w1[l * HD + 256]
                + cen_s[a][l + 64] * w1[(l + 64) * HD + 256];
        #pragma unroll
        for (int m = 1; m < 64; m <<= 1) p += __shfl_xor(p, m);
        if (l == 0) c1ws[(size_t)(i0 + a) * HD + 256] = p + b1[256];
    }
}

// ---------------- edge GEMM via MFMA (bf16 split-2, 3 MFMA per tile) ----------------
// Per block: 4 atoms, 4 waves; wave w covers column tiles [4w, 4w+4).
// S[atom][col] = sum_e leaky( (NBR@W1b)[e,col] + c1[atom][col] + d[e]*w1[256][col] )
__global__ __launch_bounds__(256) void edge_mfma_r5(
    const unsigned short* __restrict__ srcHi, const unsigned short* __restrict__ srcLo,
    const unsigned short* __restrict__ pBhi, const unsigned short* __restrict__ pBlo,
    const int* __restrict__ nidx, const float* __restrict__ ndist,
    const float* __restrict__ c1ws, const float* __restrict__ w1,
    float* __restrict__ Sws)
{
    const int t  = threadIdx.x;
    const int l  = t & 63;
    const int wv = t >> 6;
    const int i0 = blockIdx.x * 4;
    const int lg = l >> 4, li = l & 15;

    f32x4 acc[4][4];                    // [atom][ctile]
    #pragma unroll
    for (int a = 0; a < 4; ++a)
        #pragma unroll
        for (int c = 0; c < 4; ++c)
            acc[a][c] = (f32x4){0.f, 0.f, 0.f, 0.f};

    int rowIdx[4];
    #pragma unroll
    for (int a = 0; a < 4; ++a) rowIdx[a] = nidx[(i0 + a) * KNN + li];

    #pragma unroll
    for (int ks = 0; ks < 4; ++ks) {
        short8v ah[4], al[4];
        #pragma unroll
        for (int a = 0; a < 4; ++a) {
            const int eo = rowIdx[a] * DIM + ks * 32 + lg * 8;
            ah[a] = *(const short8v*)(srcHi + eo);
            al[a] = *(const short8v*)(srcLo + eo);
        }
        #pragma unroll
        for (int c = 0; c < 4; ++c) {
            const int ct = wv * 4 + c;
            const int boff = ((ct * 4 + ks) * 64 + l) * 8;
            short8v bh = *(const short8v*)(pBhi + boff);
            short8v bl = *(const short8v*)(pBlo + boff);
            #pragma unroll
            for (int a = 0; a < 4; ++a) {
                acc[a][c] = __builtin_amdgcn_mfma_f32_16x16x32_bf16(ah[a], bh, acc[a][c], 0, 0, 0);
                acc[a][c] = __builtin_amdgcn_mfma_f32_16x16x32_bf16(ah[a], bl, acc[a][c], 0, 0, 0);
                acc[a][c] = __builtin_amdgcn_mfma_f32_16x16x32_bf16(al[a], bh, acc[a][c], 0, 0, 0);
            }
        }
    }

    // epilogue: + c1 + d*w1d, leaky, sum over 16 edges
    f32x4 dv[4];
    #pragma unroll
    for (int a = 0; a < 4; ++a)
        dv[a] = *(const f32x4*)&ndist[(i0 + a) * KNN + lg * 4];

    #pragma unroll
    for (int c = 0; c < 4; ++c) {
        const int col = (wv * 4 + c) * 16 + li;
        const float w1d = w1[256 * HD + col];
        #pragma unroll
        for (int a = 0; a < 4; ++a) {
            const float c1v = c1ws[(size_t)(i0 + a) * HD + col];
            float s = 0.f;
            #pragma unroll
            for (int r = 0; r < 4; ++r) {
                // C layout: row(edge) = lg*4 + r, col = li (+16*ct)
                float h = acc[a][c][r] + c1v + dv[a][r] * w1d;
                s += leakyf(h);
            }
            s += __shfl_xor(s, 16);
            s += __shfl_xor(s, 32);
            if (lg == 0) Sws[(size_t)(i0 + a) * 256 + col] = s;
        }
    }
}

// ---------------- stage D: msg = S@w2 + 16*b2 (+ col-256 term); GN; residual ----------------
__global__ __launch_bounds__(256) void stage_d_r5(
    const float* __restrict__ centers, const float* __restrict__ srcf,
    const int* __restrict__ nidx, const float* __restrict__ ndist,
    const float* __restrict__ Sws, const float* __restrict__ c1ws,
    const float* __restrict__ w1,
    const float* __restrict__ w2, const float* __restrict__ b2,
    const float* __restrict__ gw, const float* __restrict__ gb,
    float* __restrict__ dst)
{
    const int t = threadIdx.x;
    const int i0 = blockIdx.x * 2;
    __shared__ __align__(16) float S_s[2][260];
    __shared__ __align__(16) float h256_s[2][KNN];
    __shared__ float S256_s[2];

    // stage S rows (cols 0..255)
    if (t < 128) {
        int a = t >> 6, q = t & 63;
        *(f32x4*)&S_s[a][q * 4] = *(const f32x4*)&Sws[(size_t)(i0 + a) * 256 + q * 4];
    }

    // hidden column 256: e = t>>4, kk = t&15, both atoms
    {
        const int e = t >> 4, kk = t & 15;
        const int r0 = nidx[(i0 + 0) * KNN + e];
        const int r1 = nidx[(i0 + 1) * KNN + e];
        float p0 = 0.f, p1 = 0.f;
        #pragma unroll
        for (int m = 0; m < 8; ++m) {
            const int k = kk + 16 * m;
            const float wc = w1[(128 + k) * HD + 256];
            p0 = fmaf(srcf[r0 * DIM + k], wc, p0);
            p1 = fmaf(srcf[r1 * DIM + k], wc, p1);
        }
        #pragma unroll
        for (int m = 1; m < 16; m <<= 1) {
            p0 += __shfl_xor(p0, m);
            p1 += __shfl_xor(p1, m);
        }
        if (kk == 0) {
            const float wt = w1[256 * HD + 256];
            h256_s[0][e] = leakyf(c1ws[(size_t)(i0 + 0) * HD + 256] + ndist[(i0 + 0) * KNN + e] * wt + p0);
            h256_s[1][e] = leakyf(c1ws[(size_t)(i0 + 1) * HD + 256] + ndist[(i0 + 1) * KNN + e] * wt + p1);
        }
    }
    __syncthreads();
    if (t < 2) {
        float s = 0.f;
        #pragma unroll
        for (int e = 0; e < KNN; ++e) s += h256_s[t][e];
        S256_s[t] = s;
    }
    __syncthreads();

    const int a = t >> 7, j = t & 127;
    float macc = 16.0f * b2[j];
    #pragma unroll 2
    for (int k = 0; k < 256; k += 4) {
        float4 sv = *(const float4*)&S_s[a][k];
        macc = fmaf(sv.x, w2[(k + 0) * DIM + j], macc);
        macc = fmaf(sv.y, w2[(k + 1) * DIM + j], macc);
        macc = fmaf(sv.z, w2[(k + 2) * DIM + j], macc);
        macc = fmaf(sv.w, w2[(k + 3) * DIM + j], macc);
    }
    macc = fmaf(S256_s[a], w2[256 * DIM + j], macc);

    // GroupNorm(groups=2): wave = (atom, 64-channel group)
    float s = macc;
    #pragma unroll
    for (int m = 1; m < 64; m <<= 1) s += __shfl_xor(s, m);
    float mu = s * (1.0f / 64.0f);
    float d = macc - mu;
    float ss = d * d;
    #pragma unroll
    for (int m = 1; m < 64; m <<= 1) ss += __shfl_xor(ss, m);
    float var = ss * (1.0f / 64.0f);
    float xn = d * rsqrtf(var + GN_EPS);
    float y = fmaf(xn, gw[j], gb[j]);
    dst[(i0 + a) * DIM + j] = centers[(i0 + a) * DIM + j] + leakyf(y);
}

extern "C" void kernel_launch(void* const* d_in, const int* in_sizes, int n_in,
                              void* d_out, int out_size, void* d_ws, size_t ws_size,
                              hipStream_t stream)
{
    const size_t out_bytes = (size_t)out_size * sizeof(float);
    if (n_in != 21) { (void)hipMemsetAsync(d_out, 0x43, out_bytes, stream); return; }

    // ---- workspace layout ----
    const size_t n_atoms_f = (size_t)NAT * DIM;          // 524288
    const size_t n_emb_f   = (size_t)NXQ * DIM;          // 1048576
    const size_t n_c1_f    = (size_t)NXQ * HD;           // 2105344
    const size_t n_S_f     = (size_t)NXQ * 256;          // 2097152
    const size_t n_packB   = 16 * 4 * 64 * 8;            // 32768 ushorts per layer per split
    const size_t floats_needed = n_atoms_f * 2 + n_emb_f
        + (size_t)NAT * KNN * 2 + (size_t)NXQ * KNN * 2 + n_c1_f + n_S_f;
    const size_t ushorts_needed = n_atoms_f * 2 + n_packB * 12;
    if (ws_size < floats_needed * 4 + ushorts_needed * 2 + 64) {
        (void)hipMemsetAsync(d_out, 0x41, out_bytes, stream);
        return;
    }

    const float* xyz    = (const float*)d_in[0];
    const float* axyz   = (const float*)d_in[1];
    const float* af     = (const float*)d_in[2];
    const int*   xbatch = (const int*)d_in[3];
    const int*   abatch = (const int*)d_in[4];
    const float* tw1    = (const float*)d_in[5];
    const float* tb1    = (const float*)d_in[6];
    const float* tw2    = (const float*)d_in[7];
    const float* tb2    = (const float*)d_in[8];
    const float* aa_w1  = (const float*)d_in[9];
    const float* aa_b1  = (const float*)d_in[10];
    const float* aa_w2  = (const float*)d_in[11];
    const float* aa_b2  = (const float*)d_in[12];
    const float* aa_gw  = (const float*)d_in[13];
    const float* aa_gb  = (const float*)d_in[14];
    const float* ae_w1  = (const float*)d_in[15];
    const float* ae_b1  = (const float*)d_in[16];
    const float* ae_w2  = (const float*)d_in[17];
    const float* ae_b2  = (const float*)d_in[18];
    const float* ae_gw  = (const float*)d_in[19];
    const float* ae_gb  = (const float*)d_in[20];

    float* fp      = (float*)d_ws;
    float* atoms_a = fp;                 fp += n_atoms_f;
    float* atoms_b = fp;                 fp += n_atoms_f;
    float* emb     = fp;                 fp += n_emb_f;
    int*   idx_aa  = (int*)fp;           fp += (size_t)NAT * KNN;
    float* dist_aa = fp;                 fp += (size_t)NAT * KNN;
    int*   idx_xa  = (int*)fp;           fp += (size_t)NXQ * KNN;
    float* dist_xa = fp;                 fp += (size_t)NXQ * KNN;
    float* c1ws    = fp;                 fp += n_c1_f;
    float* Sws     = fp;                 fp += n_S_f;
    unsigned short* up    = (unsigned short*)fp;
    unsigned short* srcHi = up;          up += n_atoms_f;
    unsigned short* srcLo = up;          up += n_atoms_f;
    unsigned short* pbHi  = up;          up += n_packB * 6;
    unsigned short* pbLo  = up;          up += n_packB * 6;

    const int NOUT = NXQ * DIM;

    // pack all 6 layers' W1b once (layers 0..2 = aa, 3..5 = ae)
    for (int li = 0; li < 6; ++li) {
        const float* w1p = (li < 3) ? (aa_w1 + (size_t)li * HD * HD)
                                    : (ae_w1 + (size_t)(li - 3) * HD * HD);
        pack_w1_r5<<<64, 64, 0, stream>>>(w1p, pbHi + (size_t)li * n_packB, pbLo + (size_t)li * n_packB);
    }

    fill_f32_r5<<<(NOUT + 255) / 256, 256, 0, stream>>>(emb, NOUT, 1.0f);
    feat_transform_r5<<<NAT, 128, 0, stream>>>(af, tw1, tb1, tw2, tb2, atoms_a);
    knn_r5<<<(NAT + NXQ + 255) / 256, 256, 0, stream>>>(
        xyz, xbatch, axyz, abatch, idx_aa, dist_aa, idx_xa, dist_xa);

    // ---- atom-atom layers ----
    float* cur = atoms_a;
    float* nxt = atoms_b;
    for (int i = 0; i < NLAYER; ++i) {
        const float* w1p = aa_w1 + (size_t)i * HD * HD;
        split_bf16_r5<<<(int)(n_atoms_f + 255) / 256, 256, 0, stream>>>(cur, srcHi, srcLo, (int)n_atoms_f);
        c1_kernel_r5<<<NAT / 2, 256, 0, stream>>>(cur, w1p, aa_b1 + (size_t)i * HD, c1ws);
        edge_mfma_r5<<<NAT / 4, 256, 0, stream>>>(
            srcHi, srcLo, pbHi + (size_t)i * n_packB, pbLo + (size_t)i * n_packB,
            idx_aa, dist_aa, c1ws, w1p, Sws);
        stage_d_r5<<<NAT / 2, 256, 0, stream>>>(
            cur, cur, idx_aa, dist_aa, Sws, c1ws, w1p,
            aa_w2 + (size_t)i * HD * DIM, aa_b2 + (size_t)i * DIM,
            aa_gw + (size_t)i * DIM, aa_gb + (size_t)i * DIM, nxt);
        float* tmp = cur; cur = nxt; nxt = tmp;
    }
    const float* atoms_final = cur;

    // ---- xyz-atom layers (src fixed = atoms_final; emb updated in place) ----
    split_bf16_r5<<<(int)(n_atoms_f + 255) / 256, 256, 0, stream>>>(atoms_final, srcHi, srcLo, (int)n_atoms_f);
    for (int i = 0; i < NLAYER; ++i) {
        const int li = 3 + i;
        const float* w1p = ae_w1 + (size_t)i * HD * HD;
        c1_kernel_r5<<<NXQ / 2, 256, 0, stream>>>(emb, w1p, ae_b1 + (size_t)i * HD, c1ws);
        edge_mfma_r5<<<NXQ / 4, 256, 0, stream>>>(
            srcHi, srcLo, pbHi + (size_t)li * n_packB, pbLo + (size_t)li * n_packB,
            idx_xa, dist_xa, c1ws, w1p, Sws);
        float* dsti = (i == NLAYER - 1) ? (float*)d_out : emb;
        stage_d_r5<<<NXQ / 2, 256, 0, stream>>>(
            emb, atoms_final, idx_xa, dist_xa, Sws, c1ws, w1p,
            ae_w2 + (size_t)i * HD * DIM, ae_b2 + (size_t)i * DIM,
            ae_gw + (size_t)i * DIM, ae_gb + (size_t)i * DIM, dsti);
    }
}

// Round 6
// 763.740 us; speedup vs baseline: 1.6411x; 1.2671x over previous
//
#include <hip/hip_runtime.h>
#include <hip/hip_bf16.h>

#define NAT 4096
#define NXQ 8192
#define DIM 128
#define KNN 16
#define HD  257   // 2*DIM+1
#define NLAYER 3
#define SLOPE 0.2f
#define GN_EPS 1e-5f
#define BIGD 1e30f
#define KCAP 16   // knn: candidate slots per lane (covers segments <= 1024)

typedef __attribute__((ext_vector_type(8))) short short8v;   // 8 bf16 = 4 VGPR
typedef __attribute__((ext_vector_type(4))) float f32x4;

__device__ __forceinline__ float leakyf(float z) { return z >= 0.0f ? z : SLOPE * z; }
__device__ __forceinline__ unsigned short bf16_rn(float x) {
    unsigned u = __float_as_uint(x);
    unsigned r = (u + 0x7FFFu + ((u >> 16) & 1u)) >> 16;
    return (unsigned short)r;
}
__device__ __forceinline__ float bf16f(unsigned short h) {
    return __uint_as_float(((unsigned)h) << 16);
}
__device__ __forceinline__ unsigned long long shfl_xor_u64(unsigned long long v, int m) {
    int lo = __shfl_xor((int)(v & 0xffffffffu), m);
    int hi = __shfl_xor((int)(v >> 32), m);
    return ((unsigned long long)(unsigned)hi << 32) | (unsigned)lo;
}

// ---------------- fill ----------------
__global__ void fill_f32_r6(float* __restrict__ p, int n, float v)
{
    int i = blockIdx.x * 256 + threadIdx.x;
    if (i < n) p[i] = v;
}

// ---------------- bf16 split: x = hi + lo ----------------
__global__ void split_bf16_r6(const float* __restrict__ x,
                              unsigned short* __restrict__ hi,
                              unsigned short* __restrict__ lo, int n)
{
    int i = blockIdx.x * 256 + threadIdx.x;
    if (i < n) {
        float v = x[i];
        unsigned short h = bf16_rn(v);
        hi[i] = h;
        lo[i] = bf16_rn(v - bf16f(h));
    }
}

// ---------------- pack W1b (rows 128..255) into MFMA B-fragment order ----------------
__global__ __launch_bounds__(64) void pack_w1_r6(const float* __restrict__ w1,
                                                 unsigned short* __restrict__ bhi,
                                                 unsigned short* __restrict__ blo)
{
    const int blk = blockIdx.x;          // ct*4 + ks, 64 blocks
    const int l = threadIdx.x;
    const int col = (blk >> 2) * 16 + (l & 15);
    const int kbase = 128 + (blk & 3) * 32 + (l >> 4) * 8;
    unsigned short h8[8], l8[8];
    #pragma unroll
    for (int s = 0; s < 8; ++s) {
        float w = w1[(kbase + s) * HD + col];
        unsigned short h = bf16_rn(w);
        h8[s] = h;
        l8[s] = bf16_rn(w - bf16f(h));
    }
    const int off = (blk * 64 + l) * 8;
    #pragma unroll
    for (int s = 0; s < 8; ++s) { bhi[off + s] = h8[s]; blo[off + s] = l8[s]; }
}

// ---------------- initial per-atom feature MLP ----------------
__global__ __launch_bounds__(128) void feat_transform_r6(
    const float* __restrict__ af,
    const float* __restrict__ tw1, const float* __restrict__ tb1,
    const float* __restrict__ tw2, const float* __restrict__ tb2,
    float* __restrict__ out)
{
    const int i = blockIdx.x;
    const int t = threadIdx.x;
    __shared__ __align__(16) float a_s[DIM];
    __shared__ __align__(16) float h_s[DIM];
    a_s[t] = af[i * DIM + t];
    __syncthreads();
    float acc = tb1[t];
    #pragma unroll 2
    for (int k = 0; k < DIM; k += 4) {
        float4 v = *(const float4*)&a_s[k];
        acc = fmaf(v.x, tw1[(k + 0) * DIM + t], acc);
        acc = fmaf(v.y, tw1[(k + 1) * DIM + t], acc);
        acc = fmaf(v.z, tw1[(k + 2) * DIM + t], acc);
        acc = fmaf(v.w, tw1[(k + 3) * DIM + t], acc);
    }
    h_s[t] = leakyf(acc);
    __syncthreads();
    float acc2 = tb2[t];
    #pragma unroll 2
    for (int k = 0; k < DIM; k += 4) {
        float4 v = *(const float4*)&h_s[k];
        acc2 = fmaf(v.x, tw2[(k + 0) * DIM + t], acc2);
        acc2 = fmaf(v.y, tw2[(k + 1) * DIM + t], acc2);
        acc2 = fmaf(v.z, tw2[(k + 2) * DIM + t], acc2);
        acc2 = fmaf(v.w, tw2[(k + 3) * DIM + t], acc2);
    }
    out[i * DIM + t] = acc2;
}

// ---------------- batch segment bounds (B=8 -> 9 entries) ----------------
__global__ __launch_bounds__(64) void batch_starts_r6(const int* __restrict__ abatch,
                                                      int* __restrict__ starts)
{
    int t = threadIdx.x;
    if (t <= 8) {
        int lo = 0, hi = NAT;
        while (lo < hi) { int m = (lo + hi) >> 1; if (abatch[m] < t) lo = m + 1; else hi = m; }
        starts[t] = lo;
    }
}

// ---------------- wave-parallel KNN: one wave per query ----------------
__global__ __launch_bounds__(256) void knn_r6(
    const float* __restrict__ xyz, const int* __restrict__ xbatch,
    const float* __restrict__ axyz, const int* __restrict__ abatch,
    const int* __restrict__ starts,
    int* __restrict__ idx_aa, float* __restrict__ dist_aa,
    int* __restrict__ idx_xa, float* __restrict__ dist_xa)
{
    const int w = blockIdx.x * 4 + (threadIdx.x >> 6);
    if (w >= NAT + NXQ) return;
    const int l = threadIdx.x & 63;
    const bool is_aa = w < NAT;
    const int q = is_aa ? w : w - NAT;
    float qx, qy, qz; int qb;
    if (is_aa) { qx = axyz[3 * q]; qy = axyz[3 * q + 1]; qz = axyz[3 * q + 2]; qb = abatch[q]; }
    else       { qx = xyz[3 * q];  qy = xyz[3 * q + 1];  qz = xyz[3 * q + 2];  qb = xbatch[q]; }
    const int lo = starts[qb];
    const int hi = starts[qb + 1];

    // build per-lane candidate distances (slot s -> j = lo + s*64 + l)
    float d[KCAP];
    #pragma unroll
    for (int s = 0; s < KCAP; ++s) {
        const int j = lo + s * 64 + l;
        float d2 = BIGD;
        if (j < hi && !(is_aa && j == q)) {
            float dx = qx - axyz[3 * j];
            float dy = qy - axyz[3 * j + 1];
            float dz = qz - axyz[3 * j + 2];
            d2 = dx * dx + dy * dy + dz * dz;
        }
        d[s] = d2;
    }

    // 16 rounds of wave-wide argmin with (d2, j) lexicographic order
    unsigned mask = 0;
    unsigned long long outk = 0;
    #pragma unroll 1
    for (int it = 0; it < KNN; ++it) {
        float bd = BIGD; int bs = 0;
        #pragma unroll
        for (int s = 0; s < KCAP; ++s) {
            bool c = !((mask >> s) & 1u) && d[s] < bd;
            bd = c ? d[s] : bd;
            bs = c ? s : bs;
        }
        const int bj = lo + bs * 64 + l;
        unsigned long long mykey = ((unsigned long long)__float_as_uint(bd) << 32) | (unsigned)bj;
        unsigned long long key = mykey;
        #pragma unroll
        for (int m = 32; m >= 1; m >>= 1) {
            unsigned long long o = shfl_xor_u64(key, m);
            key = (o < key) ? o : key;
        }
        if (key == mykey) mask |= 1u << bs;   // unique j -> exactly one owner
        if (l == it) outk = key;
    }

    if (l < KNN) {
        unsigned ju = (unsigned)(outk & 0xffffffffu);
        float dw = __uint_as_float((unsigned)(outk >> 32));
        int jc = (ju >= (unsigned)NAT) ? 0 : (int)ju;   // safety clamp
        int*   ip = is_aa ? (idx_aa + q * KNN)  : (idx_xa + q * KNN);
        float* dp = is_aa ? (dist_aa + q * KNN) : (dist_xa + q * KNN);
        ip[l] = jc;
        dp[l] = dw;
    }
}

// ---------------- c1 = b1 + center @ w1[0:128,:] (cols 0..256), 8 atoms/block ----------------
__global__ __launch_bounds__(256) void c1_r6(
    const float* __restrict__ centers, const float* __restrict__ w1,
    const float* __restrict__ b1, float* __restrict__ c1ws)
{
    const int t = threadIdx.x;
    const int i0 = blockIdx.x * 8;
    __shared__ __align__(16) float cen_s[8][DIM];
    #pragma unroll
    for (int it = 0; it < 4; ++it) {
        int lin = it * 256 + t;
        int a = lin >> 7, j = lin & 127;
        cen_s[a][j] = centers[(size_t)(i0 + a) * DIM + j];
    }
    __syncthreads();

    float acc[8];
    {
        const float b = b1[t];
        #pragma unroll
        for (int a = 0; a < 8; ++a) acc[a] = b;
    }
    #pragma unroll 2
    for (int k = 0; k < DIM; k += 4) {
        float w0 = w1[(k + 0) * HD + t];
        float wa = w1[(k + 1) * HD + t];
        float wb = w1[(k + 2) * HD + t];
        float wc = w1[(k + 3) * HD + t];
        #pragma unroll
        for (int a = 0; a < 8; ++a) {
            float4 c = *(const float4*)&cen_s[a][k];
            acc[a] = fmaf(c.x, w0, acc[a]);
            acc[a] = fmaf(c.y, wa, acc[a]);
            acc[a] = fmaf(c.z, wb, acc[a]);
            acc[a] = fmaf(c.w, wc, acc[a]);
        }
    }
    #pragma unroll
    for (int a = 0; a < 8; ++a)
        c1ws[(size_t)(i0 + a) * HD + t] = acc[a];

    // column 256: 32 lanes per atom
    {
        const int a = t >> 5, l32 = t & 31;
        float p = 0.f;
        #pragma unroll
        for (int m = 0; m < 4; ++m) {
            const int k = l32 + 32 * m;
            p = fmaf(cen_s[a][k], w1[k * HD + 256], p);
        }
        #pragma unroll
        for (int m = 1; m < 32; m <<= 1) p += __shfl_xor(p, m);
        if (l32 == 0) c1ws[(size_t)(i0 + a) * HD + 256] = p + b1[256];
    }
}

// ---------------- edge GEMM via MFMA (bf16 split-2, 3 MFMA per tile) ----------------
__global__ __launch_bounds__(256) void edge_mfma_r6(
    const unsigned short* __restrict__ srcHi, const unsigned short* __restrict__ srcLo,
    const unsigned short* __restrict__ pBhi, const unsigned short* __restrict__ pBlo,
    const int* __restrict__ nidx, const float* __restrict__ ndist,
    const float* __restrict__ c1ws, const float* __restrict__ w1,
    float* __restrict__ Sws)
{
    const int t  = threadIdx.x;
    const int l  = t & 63;
    const int wv = t >> 6;
    const int i0 = blockIdx.x * 4;
    const int lg = l >> 4, li = l & 15;

    f32x4 acc[4][4];                    // [atom][ctile]
    #pragma unroll
    for (int a = 0; a < 4; ++a)
        #pragma unroll
        for (int c = 0; c < 4; ++c)
            acc[a][c] = (f32x4){0.f, 0.f, 0.f, 0.f};

    int rowIdx[4];
    #pragma unroll
    for (int a = 0; a < 4; ++a) rowIdx[a] = nidx[(i0 + a) * KNN + li];

    #pragma unroll
    for (int ks = 0; ks < 4; ++ks) {
        short8v ah[4], al[4];
        #pragma unroll
        for (int a = 0; a < 4; ++a) {
            const int eo = rowIdx[a] * DIM + ks * 32 + lg * 8;
            ah[a] = *(const short8v*)(srcHi + eo);
            al[a] = *(const short8v*)(srcLo + eo);
        }
        #pragma unroll
        for (int c = 0; c < 4; ++c) {
            const int ct = wv * 4 + c;
            const int boff = ((ct * 4 + ks) * 64 + l) * 8;
            short8v bh = *(const short8v*)(pBhi + boff);
            short8v bl = *(const short8v*)(pBlo + boff);
            #pragma unroll
            for (int a = 0; a < 4; ++a) {
                acc[a][c] = __builtin_amdgcn_mfma_f32_16x16x32_bf16(ah[a], bh, acc[a][c], 0, 0, 0);
                acc[a][c] = __builtin_amdgcn_mfma_f32_16x16x32_bf16(ah[a], bl, acc[a][c], 0, 0, 0);
                acc[a][c] = __builtin_amdgcn_mfma_f32_16x16x32_bf16(al[a], bh, acc[a][c], 0, 0, 0);
            }
        }
    }

    // epilogue: + c1 + d*w1d, leaky, sum over 16 edges
    f32x4 dv[4];
    #pragma unroll
    for (int a = 0; a < 4; ++a)
        dv[a] = *(const f32x4*)&ndist[(i0 + a) * KNN + lg * 4];

    #pragma unroll
    for (int c = 0; c < 4; ++c) {
        const int col = (wv * 4 + c) * 16 + li;
        const float w1d = w1[256 * HD + col];
        #pragma unroll
        for (int a = 0; a < 4; ++a) {
            const float c1v = c1ws[(size_t)(i0 + a) * HD + col];
            float s = 0.f;
            #pragma unroll
            for (int r = 0; r < 4; ++r) {
                float h = acc[a][c][r] + c1v + dv[a][r] * w1d;
                s += leakyf(h);
            }
            s += __shfl_xor(s, 16);
            s += __shfl_xor(s, 32);
            if (lg == 0) Sws[(size_t)(i0 + a) * 256 + col] = s;
        }
    }
}

// ---------------- stage D: msg = S@w2 + 16*b2 (+ col-256 term); GN; residual ----------------
// 8 atoms per block.
__global__ __launch_bounds__(256) void stage_d_r6(
    const float* __restrict__ centers, const float* __restrict__ srcf,
    const int* __restrict__ nidx, const float* __restrict__ ndist,
    const float* __restrict__ Sws, const float* __restrict__ c1ws,
    const float* __restrict__ w1,
    const float* __restrict__ w2, const float* __restrict__ b2,
    const float* __restrict__ gw, const float* __restrict__ gb,
    float* __restrict__ dst)
{
    const int t = threadIdx.x;
    const int i0 = blockIdx.x * 8;
    __shared__ __align__(16) float S_s[8][260];
    __shared__ __align__(16) float w1d_s[DIM];   // w1[128+k][256]
    __shared__ __align__(16) float h256_s[8][KNN];
    __shared__ float S256_s[8];

    // stage S rows (8 atoms x 256 cols) as f32x4
    #pragma unroll
    for (int it = 0; it < 2; ++it) {
        int lin = it * 256 + t;                  // 0..511 f32x4 slots
        int a = lin >> 6, qd = lin & 63;
        *(f32x4*)&S_s[a][qd * 4] = *(const f32x4*)&Sws[(size_t)(i0 + a) * 256 + qd * 4];
    }
    if (t < DIM) w1d_s[t] = w1[(128 + t) * HD + 256];
    __syncthreads();

    // hidden column 256: a = t>>5, e = (t>>1)&15, half h = t&1 over k = h+2m
    {
        const int a = t >> 5, e = (t >> 1) & 15, hh = t & 1;
        const int r = nidx[(i0 + a) * KNN + e];
        float p = 0.f;
        #pragma unroll 8
        for (int m = 0; m < 64; ++m) {
            const int k = hh + 2 * m;
            p = fmaf(srcf[(size_t)r * DIM + k], w1d_s[k], p);
        }
        p += __shfl_xor(p, 1);
        if (hh == 0) {
            const float wt = w1[256 * HD + 256];
            h256_s[a][e] = leakyf(c1ws[(size_t)(i0 + a) * HD + 256]
                                  + ndist[(i0 + a) * KNN + e] * wt + p);
        }
    }
    __syncthreads();
    if (t < 8) {
        float s = 0.f;
        #pragma unroll
        for (int e = 0; e < KNN; ++e) s += h256_s[t][e];
        S256_s[t] = s;
    }
    __syncthreads();

    // main: thread covers col j for atoms abase, abase+2, abase+4, abase+6
    const int j = t & 127, abase = t >> 7;
    float macc0 = 16.0f * b2[j], macc1 = macc0, macc2 = macc0, macc3 = macc0;
    #pragma unroll 2
    for (int k = 0; k < 256; k += 4) {
        float w0 = w2[(k + 0) * DIM + j];
        float wa = w2[(k + 1) * DIM + j];
        float wb = w2[(k + 2) * DIM + j];
        float wc = w2[(k + 3) * DIM + j];
        f32x4 s0 = *(const f32x4*)&S_s[abase + 0][k];
        f32x4 s1 = *(const f32x4*)&S_s[abase + 2][k];
        f32x4 s2 = *(const f32x4*)&S_s[abase + 4][k];
        f32x4 s3 = *(const f32x4*)&S_s[abase + 6][k];
        macc0 = fmaf(s0[0], w0, macc0); macc0 = fmaf(s0[1], wa, macc0);
        macc0 = fmaf(s0[2], wb, macc0); macc0 = fmaf(s0[3], wc, macc0);
        macc1 = fmaf(s1[0], w0, macc1); macc1 = fmaf(s1[1], wa, macc1);
        macc1 = fmaf(s1[2], wb, macc1); macc1 = fmaf(s1[3], wc, macc1);
        macc2 = fmaf(s2[0], w0, macc2); macc2 = fmaf(s2[1], wa, macc2);
        macc2 = fmaf(s2[2], wb, macc2); macc2 = fmaf(s2[3], wc, macc2);
        macc3 = fmaf(s3[0], w0, macc3); macc3 = fmaf(s3[1], wa, macc3);
        macc3 = fmaf(s3[2], wb, macc3); macc3 = fmaf(s3[3], wc, macc3);
    }
    {
        const float w256 = w2[256 * DIM + j];
        macc0 = fmaf(S256_s[abase + 0], w256, macc0);
        macc1 = fmaf(S256_s[abase + 2], w256, macc1);
        macc2 = fmaf(S256_s[abase + 4], w256, macc2);
        macc3 = fmaf(S256_s[abase + 6], w256, macc3);
    }

    // GroupNorm: each wave handles one 64-col group of 4 atoms independently
    const float gwj = gw[j], gbj = gb[j];
    float m0 = macc0, m1 = macc1, m2 = macc2, m3 = macc3;
    #pragma unroll
    for (int m = 1; m < 64; m <<= 1) {
        m0 += __shfl_xor(m0, m); m1 += __shfl_xor(m1, m);
        m2 += __shfl_xor(m2, m); m3 += __shfl_xor(m3, m);
    }
    const float mu0 = m0 * (1.f / 64.f), mu1 = m1 * (1.f / 64.f);
    const float mu2 = m2 * (1.f / 64.f), mu3 = m3 * (1.f / 64.f);
    float d0 = macc0 - mu0, d1 = macc1 - mu1, d2 = macc2 - mu2, d3 = macc3 - mu3;
    float v0 = d0 * d0, v1 = d1 * d1, v2 = d2 * d2, v3 = d3 * d3;
    #pragma unroll
    for (int m = 1; m < 64; m <<= 1) {
        v0 += __shfl_xor(v0, m); v1 += __shfl_xor(v1, m);
        v2 += __shfl_xor(v2, m); v3 += __shfl_xor(v3, m);
    }
    v0 *= (1.f / 64.f); v1 *= (1.f / 64.f); v2 *= (1.f / 64.f); v3 *= (1.f / 64.f);
    const float y0 = fmaf(d0 * rsqrtf(v0 + GN_EPS), gwj, gbj);
    const float y1 = fmaf(d1 * rsqrtf(v1 + GN_EPS), gwj, gbj);
    const float y2 = fmaf(d2 * rsqrtf(v2 + GN_EPS), gwj, gbj);
    const float y3 = fmaf(d3 * rsqrtf(v3 + GN_EPS), gwj, gbj);
    dst[(size_t)(i0 + abase + 0) * DIM + j] = centers[(size_t)(i0 + abase + 0) * DIM + j] + leakyf(y0);
    dst[(size_t)(i0 + abase + 2) * DIM + j] = centers[(size_t)(i0 + abase + 2) * DIM + j] + leakyf(y1);
    dst[(size_t)(i0 + abase + 4) * DIM + j] = centers[(size_t)(i0 + abase + 4) * DIM + j] + leakyf(y2);
    dst[(size_t)(i0 + abase + 6) * DIM + j] = centers[(size_t)(i0 + abase + 6) * DIM + j] + leakyf(y3);
}

extern "C" void kernel_launch(void* const* d_in, const int* in_sizes, int n_in,
                              void* d_out, int out_size, void* d_ws, size_t ws_size,
                              hipStream_t stream)
{
    const size_t out_bytes = (size_t)out_size * sizeof(float);
    if (n_in != 21) { (void)hipMemsetAsync(d_out, 0x43, out_bytes, stream); return; }

    // ---- workspace layout ----
    const size_t n_atoms_f = (size_t)NAT * DIM;          // 524288
    const size_t n_emb_f   = (size_t)NXQ * DIM;          // 1048576
    const size_t n_c1_f    = (size_t)NXQ * HD;           // 2105344
    const size_t n_S_f     = (size_t)NXQ * 256;          // 2097152
    const size_t n_packB   = 16 * 4 * 64 * 8;            // 32768 ushorts / layer / split
    const size_t floats_needed = n_atoms_f * 2 + n_emb_f
        + (size_t)NAT * KNN * 2 + (size_t)NXQ * KNN * 2 + n_c1_f + n_S_f + 16;
    const size_t ushorts_needed = n_atoms_f * 2 + n_packB * 12;
    if (ws_size < floats_needed * 4 + ushorts_needed * 2 + 64) {
        (void)hipMemsetAsync(d_out, 0x41, out_bytes, stream);
        return;
    }

    const float* xyz    = (const float*)d_in[0];
    const float* axyz   = (const float*)d_in[1];
    const float* af     = (const float*)d_in[2];
    const int*   xbatch = (const int*)d_in[3];
    const int*   abatch = (const int*)d_in[4];
    const float* tw1    = (const float*)d_in[5];
    const float* tb1    = (const float*)d_in[6];
    const float* tw2    = (const float*)d_in[7];
    const float* tb2    = (const float*)d_in[8];
    const float* aa_w1  = (const float*)d_in[9];
    const float* aa_b1  = (const float*)d_in[10];
    const float* aa_w2  = (const float*)d_in[11];
    const float* aa_b2  = (const float*)d_in[12];
    const float* aa_gw  = (const float*)d_in[13];
    const float* aa_gb  = (const float*)d_in[14];
    const float* ae_w1  = (const float*)d_in[15];
    const float* ae_b1  = (const float*)d_in[16];
    const float* ae_w2  = (const float*)d_in[17];
    const float* ae_b2  = (const float*)d_in[18];
    const float* ae_gw  = (const float*)d_in[19];
    const float* ae_gb  = (const float*)d_in[20];

    float* fp      = (float*)d_ws;
    float* atoms_a = fp;                 fp += n_atoms_f;
    float* atoms_b = fp;                 fp += n_atoms_f;
    float* emb     = fp;                 fp += n_emb_f;
    int*   idx_aa  = (int*)fp;           fp += (size_t)NAT * KNN;
    float* dist_aa = fp;                 fp += (size_t)NAT * KNN;
    int*   idx_xa  = (int*)fp;           fp += (size_t)NXQ * KNN;
    float* dist_xa = fp;                 fp += (size_t)NXQ * KNN;
    float* c1ws    = fp;                 fp += n_c1_f;
    float* Sws     = fp;                 fp += n_S_f;
    int*   bstarts = (int*)fp;           fp += 16;
    unsigned short* up    = (unsigned short*)fp;
    unsigned short* srcHi = up;          up += n_atoms_f;
    unsigned short* srcLo = up;          up += n_atoms_f;
    unsigned short* pbHi  = up;          up += n_packB * 6;
    unsigned short* pbLo  = up;          up += n_packB * 6;

    const int NOUT = NXQ * DIM;

    // pack all 6 layers' W1b once
    for (int li = 0; li < 6; ++li) {
        const float* w1p = (li < 3) ? (aa_w1 + (size_t)li * HD * HD)
                                    : (ae_w1 + (size_t)(li - 3) * HD * HD);
        pack_w1_r6<<<64, 64, 0, stream>>>(w1p, pbHi + (size_t)li * n_packB, pbLo + (size_t)li * n_packB);
    }

    fill_f32_r6<<<(NOUT + 255) / 256, 256, 0, stream>>>(emb, NOUT, 1.0f);
    feat_transform_r6<<<NAT, 128, 0, stream>>>(af, tw1, tb1, tw2, tb2, atoms_a);
    batch_starts_r6<<<1, 64, 0, stream>>>(abatch, bstarts);
    knn_r6<<<(NAT + NXQ + 3) / 4, 256, 0, stream>>>(
        xyz, xbatch, axyz, abatch, bstarts, idx_aa, dist_aa, idx_xa, dist_xa);

    // ---- atom-atom layers ----
    float* cur = atoms_a;
    float* nxt = atoms_b;
    for (int i = 0; i < NLAYER; ++i) {
        const float* w1p = aa_w1 + (size_t)i * HD * HD;
        split_bf16_r6<<<(int)(n_atoms_f + 255) / 256, 256, 0, stream>>>(cur, srcHi, srcLo, (int)n_atoms_f);
        c1_r6<<<NAT / 8, 256, 0, stream>>>(cur, w1p, aa_b1 + (size_t)i * HD, c1ws);
        edge_mfma_r6<<<NAT / 4, 256, 0, stream>>>(
            srcHi, srcLo, pbHi + (size_t)i * n_packB, pbLo + (size_t)i * n_packB,
            idx_aa, dist_aa, c1ws, w1p, Sws);
        stage_d_r6<<<NAT / 8, 256, 0, stream>>>(
            cur, cur, idx_aa, dist_aa, Sws, c1ws, w1p,
            aa_w2 + (size_t)i * HD * DIM, aa_b2 + (size_t)i * DIM,
            aa_gw + (size_t)i * DIM, aa_gb + (size_t)i * DIM, nxt);
        float* tmp = cur; cur = nxt; nxt = tmp;
    }
    const float* atoms_final = cur;

    // ---- xyz-atom layers ----
    split_bf16_r6<<<(int)(n_atoms_f + 255) / 256, 256, 0, stream>>>(atoms_final, srcHi, srcLo, (int)n_atoms_f);
    for (int i = 0; i < NLAYER; ++i) {
        const int li = 3 + i;
        const float* w1p = ae_w1 + (size_t)i * HD * HD;
        c1_r6<<<NXQ / 8, 256, 0, stream>>>(emb, w1p, ae_b1 + (size_t)i * HD, c1ws);
        edge_mfma_r6<<<NXQ / 4, 256, 0, stream>>>(
            srcHi, srcLo, pbHi + (size_t)li * n_packB, pbLo + (size_t)li * n_packB,
            idx_xa, dist_xa, c1ws, w1p, Sws);
        float* dsti = (i == NLAYER - 1) ? (float*)d_out : emb;
        stage_d_r6<<<NXQ / 8, 256, 0, stream>>>(
            emb, atoms_final, idx_xa, dist_xa, Sws, c1ws, w1p,
            ae_w2 + (size_t)i * HD * DIM, ae_b2 + (size_t)i * DIM,
            ae_gw + (size_t)i * DIM, ae_gb + (size_t)i * DIM, dsti);
    }
}

// Round 7
// 668.707 us; speedup vs baseline: 1.8744x; 1.1421x over previous
//
#include <hip/hip_runtime.h>
#include <hip/hip_bf16.h>

#define NAT 4096
#define NXQ 8192
#define DIM 128
#define KNN 16
#define HD  257   // 2*DIM+1
#define NLAYER 3
#define SLOPE 0.2f
#define GN_EPS 1e-5f
#define BIGD 1e30f
#define KCAP 16
#define SWS_LD 260

typedef __attribute__((ext_vector_type(8))) short short8v;   // 8 bf16 = 4 VGPR
typedef __attribute__((ext_vector_type(4))) float f32x4;

__device__ __forceinline__ float leakyf(float z) { return z >= 0.0f ? z : SLOPE * z; }
__device__ __forceinline__ unsigned short bf16_rn(float x) {
    unsigned u = __float_as_uint(x);
    unsigned r = (u + 0x7FFFu + ((u >> 16) & 1u)) >> 16;
    return (unsigned short)r;
}
__device__ __forceinline__ float bf16f(unsigned short h) {
    return __uint_as_float(((unsigned)h) << 16);
}
__device__ __forceinline__ unsigned long long shfl_xor_u64(unsigned long long v, int m) {
    int lo = __shfl_xor((int)(v & 0xffffffffu), m);
    int hi = __shfl_xor((int)(v >> 32), m);
    return ((unsigned long long)(unsigned)hi << 32) | (unsigned)lo;
}

// ---------------- fill ----------------
__global__ void fill_f32_r7(float* __restrict__ p, int n, float v)
{
    int i = blockIdx.x * 256 + threadIdx.x;
    if (i < n) p[i] = v;
}

// ---------------- bf16 split: x = hi + lo ----------------
__global__ void split_bf16_r7(const float* __restrict__ x,
                              unsigned short* __restrict__ hi,
                              unsigned short* __restrict__ lo, int n)
{
    int i = blockIdx.x * 256 + threadIdx.x;
    if (i < n) {
        float v = x[i];
        unsigned short h = bf16_rn(v);
        hi[i] = h;
        lo[i] = bf16_rn(v - bf16f(h));
    }
}

// ---------------- pack W1b (rows 128..255) into MFMA B-fragment order ----------------
__global__ __launch_bounds__(64) void pack_w1_r7(const float* __restrict__ w1,
                                                 unsigned short* __restrict__ bhi,
                                                 unsigned short* __restrict__ blo)
{
    const int blk = blockIdx.x;          // ct*4 + ks, 64 blocks
    const int l = threadIdx.x;
    const int col = (blk >> 2) * 16 + (l & 15);
    const int kbase = 128 + (blk & 3) * 32 + (l >> 4) * 8;
    unsigned short h8[8], l8[8];
    #pragma unroll
    for (int s = 0; s < 8; ++s) {
        float w = w1[(kbase + s) * HD + col];
        unsigned short h = bf16_rn(w);
        h8[s] = h;
        l8[s] = bf16_rn(w - bf16f(h));
    }
    const int off = (blk * 64 + l) * 8;
    #pragma unroll
    for (int s = 0; s < 8; ++s) { bhi[off + s] = h8[s]; blo[off + s] = l8[s]; }
}

// ---------------- initial per-atom feature MLP ----------------
__global__ __launch_bounds__(128) void feat_transform_r7(
    const float* __restrict__ af,
    const float* __restrict__ tw1, const float* __restrict__ tb1,
    const float* __restrict__ tw2, const float* __restrict__ tb2,
    float* __restrict__ out)
{
    const int i = blockIdx.x;
    const int t = threadIdx.x;
    __shared__ __align__(16) float a_s[DIM];
    __shared__ __align__(16) float h_s[DIM];
    a_s[t] = af[i * DIM + t];
    __syncthreads();
    float acc = tb1[t];
    #pragma unroll 2
    for (int k = 0; k < DIM; k += 4) {
        float4 v = *(const float4*)&a_s[k];
        acc = fmaf(v.x, tw1[(k + 0) * DIM + t], acc);
        acc = fmaf(v.y, tw1[(k + 1) * DIM + t], acc);
        acc = fmaf(v.z, tw1[(k + 2) * DIM + t], acc);
        acc = fmaf(v.w, tw1[(k + 3) * DIM + t], acc);
    }
    h_s[t] = leakyf(acc);
    __syncthreads();
    float acc2 = tb2[t];
    #pragma unroll 2
    for (int k = 0; k < DIM; k += 4) {
        float4 v = *(const float4*)&h_s[k];
        acc2 = fmaf(v.x, tw2[(k + 0) * DIM + t], acc2);
        acc2 = fmaf(v.y, tw2[(k + 1) * DIM + t], acc2);
        acc2 = fmaf(v.z, tw2[(k + 2) * DIM + t], acc2);
        acc2 = fmaf(v.w, tw2[(k + 3) * DIM + t], acc2);
    }
    out[i * DIM + t] = acc2;
}

// ---------------- batch segment bounds ----------------
__global__ __launch_bounds__(64) void batch_starts_r7(const int* __restrict__ abatch,
                                                      int* __restrict__ starts)
{
    int t = threadIdx.x;
    if (t <= 8) {
        int lo = 0, hi = NAT;
        while (lo < hi) { int m = (lo + hi) >> 1; if (abatch[m] < t) lo = m + 1; else hi = m; }
        starts[t] = lo;
    }
}

// ---------------- wave-parallel KNN: one wave per query ----------------
__global__ __launch_bounds__(256) void knn_r7(
    const float* __restrict__ xyz, const int* __restrict__ xbatch,
    const float* __restrict__ axyz, const int* __restrict__ abatch,
    const int* __restrict__ starts,
    int* __restrict__ idx_aa, float* __restrict__ dist_aa,
    int* __restrict__ idx_xa, float* __restrict__ dist_xa)
{
    const int w = blockIdx.x * 4 + (threadIdx.x >> 6);
    if (w >= NAT + NXQ) return;
    const int l = threadIdx.x & 63;
    const bool is_aa = w < NAT;
    const int q = is_aa ? w : w - NAT;
    float qx, qy, qz; int qb;
    if (is_aa) { qx = axyz[3 * q]; qy = axyz[3 * q + 1]; qz = axyz[3 * q + 2]; qb = abatch[q]; }
    else       { qx = xyz[3 * q];  qy = xyz[3 * q + 1];  qz = xyz[3 * q + 2];  qb = xbatch[q]; }
    const int lo = starts[qb];
    const int hi = starts[qb + 1];

    float d[KCAP];
    #pragma unroll
    for (int s = 0; s < KCAP; ++s) {
        const int j = lo + s * 64 + l;
        float d2 = BIGD;
        if (j < hi && !(is_aa && j == q)) {
            float dx = qx - axyz[3 * j];
            float dy = qy - axyz[3 * j + 1];
            float dz = qz - axyz[3 * j + 2];
            d2 = dx * dx + dy * dy + dz * dz;
        }
        d[s] = d2;
    }

    unsigned mask = 0;
    unsigned long long outk = 0;
    #pragma unroll 1
    for (int it = 0; it < KNN; ++it) {
        float bd = BIGD; int bs = 0;
        #pragma unroll
        for (int s = 0; s < KCAP; ++s) {
            bool c = !((mask >> s) & 1u) && d[s] < bd;
            bd = c ? d[s] : bd;
            bs = c ? s : bs;
        }
        const int bj = lo + bs * 64 + l;
        unsigned long long mykey = ((unsigned long long)__float_as_uint(bd) << 32) | (unsigned)bj;
        unsigned long long key = mykey;
        #pragma unroll
        for (int m = 32; m >= 1; m >>= 1) {
            unsigned long long o = shfl_xor_u64(key, m);
            key = (o < key) ? o : key;
        }
        if (key == mykey) mask |= 1u << bs;
        if (l == it) outk = key;
    }

    if (l < KNN) {
        unsigned ju = (unsigned)(outk & 0xffffffffu);
        float dw = __uint_as_float((unsigned)(outk >> 32));
        int jc = (ju >= (unsigned)NAT) ? 0 : (int)ju;
        int*   ip = is_aa ? (idx_aa + q * KNN)  : (idx_xa + q * KNN);
        float* dp = is_aa ? (dist_aa + q * KNN) : (dist_xa + q * KNN);
        ip[l] = jc;
        dp[l] = dw;
    }
}

// ---------------- c1 = b1 + center @ w1[0:128,:] (cols 0..256), 8 atoms/block ----------------
__global__ __launch_bounds__(256) void c1_r7(
    const float* __restrict__ centers, const float* __restrict__ w1,
    const float* __restrict__ b1, float* __restrict__ c1ws)
{
    const int t = threadIdx.x;
    const int i0 = blockIdx.x * 8;
    __shared__ __align__(16) float cen_s[8][DIM];
    #pragma unroll
    for (int it = 0; it < 4; ++it) {
        int lin = it * 256 + t;
        int a = lin >> 7, j = lin & 127;
        cen_s[a][j] = centers[(size_t)(i0 + a) * DIM + j];
    }
    __syncthreads();

    float acc[8];
    {
        const float b = b1[t];
        #pragma unroll
        for (int a = 0; a < 8; ++a) acc[a] = b;
    }
    #pragma unroll 2
    for (int k = 0; k < DIM; k += 4) {
        float w0 = w1[(k + 0) * HD + t];
        float wa = w1[(k + 1) * HD + t];
        float wb = w1[(k + 2) * HD + t];
        float wc = w1[(k + 3) * HD + t];
        #pragma unroll
        for (int a = 0; a < 8; ++a) {
            float4 c = *(const float4*)&cen_s[a][k];
            acc[a] = fmaf(c.x, w0, acc[a]);
            acc[a] = fmaf(c.y, wa, acc[a]);
            acc[a] = fmaf(c.z, wb, acc[a]);
            acc[a] = fmaf(c.w, wc, acc[a]);
        }
    }
    #pragma unroll
    for (int a = 0; a < 8; ++a)
        c1ws[(size_t)(i0 + a) * HD + t] = acc[a];

    {
        const int a = t >> 5, l32 = t & 31;
        float p = 0.f;
        #pragma unroll
        for (int m = 0; m < 4; ++m) {
            const int k = l32 + 32 * m;
            p = fmaf(cen_s[a][k], w1[k * HD + 256], p);
        }
        #pragma unroll
        for (int m = 1; m < 32; m <<= 1) p += __shfl_xor(p, m);
        if (l32 == 0) c1ws[(size_t)(i0 + a) * HD + 256] = p + b1[256];
    }
}

// ---------------- edge GEMM via MFMA, 2 atoms x 4 ctiles per wave, ks double-buffered ----
// Also computes the col-256 hidden (h256) inline on wave 0 and writes Sws[...][256].
__global__ __launch_bounds__(256) void edge_mfma_r7(
    const unsigned short* __restrict__ srcHi, const unsigned short* __restrict__ srcLo,
    const unsigned short* __restrict__ pBhi, const unsigned short* __restrict__ pBlo,
    const int* __restrict__ nidx, const float* __restrict__ ndist,
    const float* __restrict__ c1ws, const float* __restrict__ w1,
    float* __restrict__ Sws)
{
    const int t  = threadIdx.x;
    const int l  = t & 63;
    const int wv = t >> 6;
    const int i0 = blockIdx.x * 2;
    const int lg = l >> 4, li = l & 15;

    const int row0 = nidx[(i0 + 0) * KNN + li];
    const int row1 = nidx[(i0 + 1) * KNN + li];
    const int aoff0 = row0 * DIM + lg * 8;
    const int aoff1 = row1 * DIM + lg * 8;

    f32x4 acc0[4], acc1[4];
    #pragma unroll
    for (int c = 0; c < 4; ++c) {
        acc0[c] = (f32x4){0.f, 0.f, 0.f, 0.f};
        acc1[c] = (f32x4){0.f, 0.f, 0.f, 0.f};
    }

    float p0 = 0.f, p1 = 0.f;
    const bool do256 = (wv == 0);

    short8v a0hA, a0lA, a1hA, a1lA, a0hB, a0lB, a1hB, a1lB;
    short8v bhA[4], blA[4], bhB[4], blB[4];

#define LOADS_R7(a0h, a0l, a1h, a1l, bh, bl, ks) do {                         \
    a0h = *(const short8v*)(srcHi + aoff0 + (ks) * 32);                       \
    a0l = *(const short8v*)(srcLo + aoff0 + (ks) * 32);                       \
    a1h = *(const short8v*)(srcHi + aoff1 + (ks) * 32);                       \
    a1l = *(const short8v*)(srcLo + aoff1 + (ks) * 32);                       \
    _Pragma("unroll")                                                         \
    for (int c = 0; c < 4; ++c) {                                             \
        const int boff = (((wv * 4 + c) * 4 + (ks)) * 64 + l) * 8;            \
        bh[c] = *(const short8v*)(pBhi + boff);                               \
        bl[c] = *(const short8v*)(pBlo + boff);                               \
    } } while (0)

#define H256_R7(a0h, a0l, a1h, a1l, ks) do { if (do256) {                     \
    _Pragma("unroll")                                                         \
    for (int s = 0; s < 8; ++s) {                                             \
        const float wd = w1[(size_t)(128 + (ks) * 32 + lg * 8 + s) * HD + 256]; \
        p0 = fmaf(bf16f((unsigned short)a0h[s]) + bf16f((unsigned short)a0l[s]), wd, p0); \
        p1 = fmaf(bf16f((unsigned short)a1h[s]) + bf16f((unsigned short)a1l[s]), wd, p1); \
    } } } while (0)

#define STEP_R7(a0h, a0l, a1h, a1l, bh, bl) do {                              \
    _Pragma("unroll")                                                         \
    for (int c = 0; c < 4; ++c) {                                             \
        acc0[c] = __builtin_amdgcn_mfma_f32_16x16x32_bf16(a0h, bh[c], acc0[c], 0, 0, 0); \
        acc0[c] = __builtin_amdgcn_mfma_f32_16x16x32_bf16(a0h, bl[c], acc0[c], 0, 0, 0); \
        acc0[c] = __builtin_amdgcn_mfma_f32_16x16x32_bf16(a0l, bh[c], acc0[c], 0, 0, 0); \
        acc1[c] = __builtin_amdgcn_mfma_f32_16x16x32_bf16(a1h, bh[c], acc1[c], 0, 0, 0); \
        acc1[c] = __builtin_amdgcn_mfma_f32_16x16x32_bf16(a1h, bl[c], acc1[c], 0, 0, 0); \
        acc1[c] = __builtin_amdgcn_mfma_f32_16x16x32_bf16(a1l, bh[c], acc1[c], 0, 0, 0); \
    } } while (0)

    LOADS_R7(a0hA, a0lA, a1hA, a1lA, bhA, blA, 0);
    LOADS_R7(a0hB, a0lB, a1hB, a1lB, bhB, blB, 1);
    H256_R7(a0hA, a0lA, a1hA, a1lA, 0);
    STEP_R7(a0hA, a0lA, a1hA, a1lA, bhA, blA);
    LOADS_R7(a0hA, a0lA, a1hA, a1lA, bhA, blA, 2);
    H256_R7(a0hB, a0lB, a1hB, a1lB, 1);
    STEP_R7(a0hB, a0lB, a1hB, a1lB, bhB, blB);
    LOADS_R7(a0hB, a0lB, a1hB, a1lB, bhB, blB, 3);
    H256_R7(a0hA, a0lA, a1hA, a1lA, 2);
    STEP_R7(a0hA, a0lA, a1hA, a1lA, bhA, blA);
    H256_R7(a0hB, a0lB, a1hB, a1lB, 3);
    STEP_R7(a0hB, a0lB, a1hB, a1lB, bhB, blB);

#undef LOADS_R7
#undef H256_R7
#undef STEP_R7

    // epilogue: + c1 + d*w1d, leaky, sum over 16 edges
    const f32x4 dv0 = *(const f32x4*)&ndist[(i0 + 0) * KNN + lg * 4];
    const f32x4 dv1 = *(const f32x4*)&ndist[(i0 + 1) * KNN + lg * 4];
    #pragma unroll
    for (int c = 0; c < 4; ++c) {
        const int col = (wv * 4 + c) * 16 + li;
        const float w1d = w1[256 * HD + col];
        const float c10 = c1ws[(size_t)(i0 + 0) * HD + col];
        const float c11 = c1ws[(size_t)(i0 + 1) * HD + col];
        float s0 = 0.f, s1 = 0.f;
        #pragma unroll
        for (int r = 0; r < 4; ++r) {
            s0 += leakyf(acc0[c][r] + c10 + dv0[r] * w1d);
            s1 += leakyf(acc1[c][r] + c11 + dv1[r] * w1d);
        }
        s0 += __shfl_xor(s0, 16); s0 += __shfl_xor(s0, 32);
        s1 += __shfl_xor(s1, 16); s1 += __shfl_xor(s1, 32);
        if (lg == 0) {
            Sws[(size_t)(i0 + 0) * SWS_LD + col] = s0;
            Sws[(size_t)(i0 + 1) * SWS_LD + col] = s1;
        }
    }

    // col-256 hidden: S256 = sum_e leaky(c1_256 + d[e]*wt + sum_k nbr[e][k]*w1d[k])
    if (do256) {
        p0 += __shfl_xor(p0, 16); p0 += __shfl_xor(p0, 32);
        p1 += __shfl_xor(p1, 16); p1 += __shfl_xor(p1, 32);
        const float wt = w1[(size_t)256 * HD + 256];
        const float dl0 = ndist[(i0 + 0) * KNN + li];
        const float dl1 = ndist[(i0 + 1) * KNN + li];
        float h0 = leakyf(c1ws[(size_t)(i0 + 0) * HD + 256] + dl0 * wt + p0);
        float h1 = leakyf(c1ws[(size_t)(i0 + 1) * HD + 256] + dl1 * wt + p1);
        #pragma unroll
        for (int m = 1; m < 16; m <<= 1) { h0 += __shfl_xor(h0, m); h1 += __shfl_xor(h1, m); }
        if (l == 0) {
            Sws[(size_t)(i0 + 0) * SWS_LD + 256] = h0;
            Sws[(size_t)(i0 + 1) * SWS_LD + 256] = h1;
        }
    }
}

// ---------------- stage D: msg = S@w2 + 16*b2; GN; residual (8 atoms/block) ----------------
__global__ __launch_bounds__(256) void stage_d_r7(
    const float* __restrict__ centers,
    const float* __restrict__ Sws,
    const float* __restrict__ w2, const float* __restrict__ b2,
    const float* __restrict__ gw, const float* __restrict__ gb,
    float* __restrict__ dst)
{
    const int t = threadIdx.x;
    const int i0 = blockIdx.x * 8;
    __shared__ __align__(16) float S_s[8][260];

    #pragma unroll
    for (int it = 0; it < 3; ++it) {
        int lin = it * 256 + t;                   // 520 f32x4 slots (8 x 65)
        if (lin < 520) {
            int a = lin / 65, qd = lin - a * 65;
            *(f32x4*)&S_s[a][qd * 4] = *(const f32x4*)&Sws[(size_t)(i0 + a) * SWS_LD + qd * 4];
        }
    }
    __syncthreads();

    const int j = t & 127, abase = t >> 7;
    float macc0 = 16.0f * b2[j], macc1 = macc0, macc2 = macc0, macc3 = macc0;
    #pragma unroll 2
    for (int k = 0; k < 256; k += 4) {
        float w0 = w2[(k + 0) * DIM + j];
        float wa = w2[(k + 1) * DIM + j];
        float wb = w2[(k + 2) * DIM + j];
        float wc = w2[(k + 3) * DIM + j];
        f32x4 s0 = *(const f32x4*)&S_s[abase + 0][k];
        f32x4 s1 = *(const f32x4*)&S_s[abase + 2][k];
        f32x4 s2 = *(const f32x4*)&S_s[abase + 4][k];
        f32x4 s3 = *(const f32x4*)&S_s[abase + 6][k];
        macc0 = fmaf(s0[0], w0, macc0); macc0 = fmaf(s0[1], wa, macc0);
        macc0 = fmaf(s0[2], wb, macc0); macc0 = fmaf(s0[3], wc, macc0);
        macc1 = fmaf(s1[0], w0, macc1); macc1 = fmaf(s1[1], wa, macc1);
        macc1 = fmaf(s1[2], wb, macc1); macc1 = fmaf(s1[3], wc, macc1);
        macc2 = fmaf(s2[0], w0, macc2); macc2 = fmaf(s2[1], wa, macc2);
        macc2 = fmaf(s2[2], wb, macc2); macc2 = fmaf(s2[3], wc, macc2);
        macc3 = fmaf(s3[0], w0, macc3); macc3 = fmaf(s3[1], wa, macc3);
        macc3 = fmaf(s3[2], wb, macc3); macc3 = fmaf(s3[3], wc, macc3);
    }
    {
        const float w256 = w2[256 * DIM + j];
        macc0 = fmaf(S_s[abase + 0][256], w256, macc0);
        macc1 = fmaf(S_s[abase + 2][256], w256, macc1);
        macc2 = fmaf(S_s[abase + 4][256], w256, macc2);
        macc3 = fmaf(S_s[abase + 6][256], w256, macc3);
    }

    const float gwj = gw[j], gbj = gb[j];
    float m0 = macc0, m1 = macc1, m2 = macc2, m3 = macc3;
    #pragma unroll
    for (int m = 1; m < 64; m <<= 1) {
        m0 += __shfl_xor(m0, m); m1 += __shfl_xor(m1, m);
        m2 += __shfl_xor(m2, m); m3 += __shfl_xor(m3, m);
    }
    const float mu0 = m0 * (1.f / 64.f), mu1 = m1 * (1.f / 64.f);
    const float mu2 = m2 * (1.f / 64.f), mu3 = m3 * (1.f / 64.f);
    float d0 = macc0 - mu0, d1 = macc1 - mu1, d2 = macc2 - mu2, d3 = macc3 - mu3;
    float v0 = d0 * d0, v1 = d1 * d1, v2 = d2 * d2, v3 = d3 * d3;
    #pragma unroll
    for (int m = 1; m < 64; m <<= 1) {
        v0 += __shfl_xor(v0, m); v1 += __shfl_xor(v1, m);
        v2 += __shfl_xor(v2, m); v3 += __shfl_xor(v3, m);
    }
    v0 *= (1.f / 64.f); v1 *= (1.f / 64.f); v2 *= (1.f / 64.f); v3 *= (1.f / 64.f);
    const float y0 = fmaf(d0 * rsqrtf(v0 + GN_EPS), gwj, gbj);
    const float y1 = fmaf(d1 * rsqrtf(v1 + GN_EPS), gwj, gbj);
    const float y2 = fmaf(d2 * rsqrtf(v2 + GN_EPS), gwj, gbj);
    const float y3 = fmaf(d3 * rsqrtf(v3 + GN_EPS), gwj, gbj);
    dst[(size_t)(i0 + abase + 0) * DIM + j] = centers[(size_t)(i0 + abase + 0) * DIM + j] + leakyf(y0);
    dst[(size_t)(i0 + abase + 2) * DIM + j] = centers[(size_t)(i0 + abase + 2) * DIM + j] + leakyf(y1);
    dst[(size_t)(i0 + abase + 4) * DIM + j] = centers[(size_t)(i0 + abase + 4) * DIM + j] + leakyf(y2);
    dst[(size_t)(i0 + abase + 6) * DIM + j] = centers[(size_t)(i0 + abase + 6) * DIM + j] + leakyf(y3);
}

extern "C" void kernel_launch(void* const* d_in, const int* in_sizes, int n_in,
                              void* d_out, int out_size, void* d_ws, size_t ws_size,
                              hipStream_t stream)
{
    const size_t out_bytes = (size_t)out_size * sizeof(float);
    if (n_in != 21) { (void)hipMemsetAsync(d_out, 0x43, out_bytes, stream); return; }

    const size_t n_atoms_f = (size_t)NAT * DIM;
    const size_t n_emb_f   = (size_t)NXQ * DIM;
    const size_t n_c1_f    = (size_t)NXQ * HD;
    const size_t n_S_f     = (size_t)NXQ * SWS_LD;
    const size_t n_packB   = 16 * 4 * 64 * 8;
    const size_t floats_needed = n_atoms_f * 2 + n_emb_f
        + (size_t)NAT * KNN * 2 + (size_t)NXQ * KNN * 2 + n_c1_f + n_S_f + 16;
    const size_t ushorts_needed = n_atoms_f * 2 + n_packB * 12;
    if (ws_size < floats_needed * 4 + ushorts_needed * 2 + 64) {
        (void)hipMemsetAsync(d_out, 0x41, out_bytes, stream);
        return;
    }

    const float* xyz    = (const float*)d_in[0];
    const float* axyz   = (const float*)d_in[1];
    const float* af     = (const float*)d_in[2];
    const int*   xbatch = (const int*)d_in[3];
    const int*   abatch = (const int*)d_in[4];
    const float* tw1    = (const float*)d_in[5];
    const float* tb1    = (const float*)d_in[6];
    const float* tw2    = (const float*)d_in[7];
    const float* tb2    = (const float*)d_in[8];
    const float* aa_w1  = (const float*)d_in[9];
    const float* aa_b1  = (const float*)d_in[10];
    const float* aa_w2  = (const float*)d_in[11];
    const float* aa_b2  = (const float*)d_in[12];
    const float* aa_gw  = (const float*)d_in[13];
    const float* aa_gb  = (const float*)d_in[14];
    const float* ae_w1  = (const float*)d_in[15];
    const float* ae_b1  = (const float*)d_in[16];
    const float* ae_w2  = (const float*)d_in[17];
    const float* ae_b2  = (const float*)d_in[18];
    const float* ae_gw  = (const float*)d_in[19];
    const float* ae_gb  = (const float*)d_in[20];

    float* fp      = (float*)d_ws;
    float* atoms_a = fp;                 fp += n_atoms_f;
    float* atoms_b = fp;                 fp += n_atoms_f;
    float* emb     = fp;                 fp += n_emb_f;
    int*   idx_aa  = (int*)fp;           fp += (size_t)NAT * KNN;
    float* dist_aa = fp;                 fp += (size_t)NAT * KNN;
    int*   idx_xa  = (int*)fp;           fp += (size_t)NXQ * KNN;
    float* dist_xa = fp;                 fp += (size_t)NXQ * KNN;
    float* c1ws    = fp;                 fp += n_c1_f;
    float* Sws     = fp;                 fp += n_S_f;
    int*   bstarts = (int*)fp;           fp += 16;
    unsigned short* up    = (unsigned short*)fp;
    unsigned short* srcHi = up;          up += n_atoms_f;
    unsigned short* srcLo = up;          up += n_atoms_f;
    unsigned short* pbHi  = up;          up += n_packB * 6;
    unsigned short* pbLo  = up;          up += n_packB * 6;

    const int NOUT = NXQ * DIM;

    for (int li = 0; li < 6; ++li) {
        const float* w1p = (li < 3) ? (aa_w1 + (size_t)li * HD * HD)
                                    : (ae_w1 + (size_t)(li - 3) * HD * HD);
        pack_w1_r7<<<64, 64, 0, stream>>>(w1p, pbHi + (size_t)li * n_packB, pbLo + (size_t)li * n_packB);
    }

    fill_f32_r7<<<(NOUT + 255) / 256, 256, 0, stream>>>(emb, NOUT, 1.0f);
    feat_transform_r7<<<NAT, 128, 0, stream>>>(af, tw1, tb1, tw2, tb2, atoms_a);
    batch_starts_r7<<<1, 64, 0, stream>>>(abatch, bstarts);
    knn_r7<<<(NAT + NXQ + 3) / 4, 256, 0, stream>>>(
        xyz, xbatch, axyz, abatch, bstarts, idx_aa, dist_aa, idx_xa, dist_xa);

    // ---- atom-atom layers ----
    float* cur = atoms_a;
    float* nxt = atoms_b;
    for (int i = 0; i < NLAYER; ++i) {
        const float* w1p = aa_w1 + (size_t)i * HD * HD;
        split_bf16_r7<<<(int)(n_atoms_f + 255) / 256, 256, 0, stream>>>(cur, srcHi, srcLo, (int)n_atoms_f);
        c1_r7<<<NAT / 8, 256, 0, stream>>>(cur, w1p, aa_b1 + (size_t)i * HD, c1ws);
        edge_mfma_r7<<<NAT / 2, 256, 0, stream>>>(
            srcHi, srcLo, pbHi + (size_t)i * n_packB, pbLo + (size_t)i * n_packB,
            idx_aa, dist_aa, c1ws, w1p, Sws);
        stage_d_r7<<<NAT / 8, 256, 0, stream>>>(
            cur, Sws,
            aa_w2 + (size_t)i * HD * DIM, aa_b2 + (size_t)i * DIM,
            aa_gw + (size_t)i * DIM, aa_gb + (size_t)i * DIM, nxt);
        float* tmp = cur; cur = nxt; nxt = tmp;
    }
    const float* atoms_final = cur;

    // ---- xyz-atom layers ----
    split_bf16_r7<<<(int)(n_atoms_f + 255) / 256, 256, 0, stream>>>(atoms_final, srcHi, srcLo, (int)n_atoms_f);
    for (int i = 0; i < NLAYER; ++i) {
        const int li = 3 + i;
        const float* w1p = ae_w1 + (size_t)i * HD * HD;
        c1_r7<<<NXQ / 8, 256, 0, stream>>>(emb, w1p, ae_b1 + (size_t)i * HD, c1ws);
        edge_mfma_r7<<<NXQ / 2, 256, 0, stream>>>(
            srcHi, srcLo, pbHi + (size_t)li * n_packB, pbLo + (size_t)li * n_packB,
            idx_xa, dist_xa, c1ws, w1p, Sws);
        float* dsti = (i == NLAYER - 1) ? (float*)d_out : emb;
        stage_d_r7<<<NXQ / 8, 256, 0, stream>>>(
            emb, Sws,
            ae_w2 + (size_t)i * HD * DIM, ae_b2 + (size_t)i * DIM,
            ae_gw + (size_t)i * DIM, ae_gb + (size_t)i * DIM, dsti);
    }
}

// Round 8
// 463.980 us; speedup vs baseline: 2.7014x; 1.4412x over previous
//
#include <hip/hip_runtime.h>
#include <hip/hip_bf16.h>

#define NAT 4096
#define NXQ 8192
#define DIM 128
#define KNN 16
#define HD  257   // 2*DIM+1
#define NLAYER 3
#define SLOPE 0.2f
#define GN_EPS 1e-5f
#define BIGD 1e30f
#define KCAP 16
#define SWS_LD 260

typedef __attribute__((ext_vector_type(4))) float f32x4;

__device__ __forceinline__ float leakyf(float z) { return z >= 0.0f ? z : SLOPE * z; }
__device__ __forceinline__ unsigned long long shfl_xor_u64(unsigned long long v, int m) {
    int lo = __shfl_xor((int)(v & 0xffffffffu), m);
    int hi = __shfl_xor((int)(v >> 32), m);
    return ((unsigned long long)(unsigned)hi << 32) | (unsigned)lo;
}

// ---------------- fill ----------------
__global__ void fill_f32_r8(float* __restrict__ p, int n, float v)
{
    int i = blockIdx.x * 256 + threadIdx.x;
    if (i < n) p[i] = v;
}

// ---------------- initial per-atom feature MLP ----------------
__global__ __launch_bounds__(128) void feat_transform_r8(
    const float* __restrict__ af,
    const float* __restrict__ tw1, const float* __restrict__ tb1,
    const float* __restrict__ tw2, const float* __restrict__ tb2,
    float* __restrict__ out)
{
    const int i = blockIdx.x;
    const int t = threadIdx.x;
    __shared__ __align__(16) float a_s[DIM];
    __shared__ __align__(16) float h_s[DIM];
    a_s[t] = af[i * DIM + t];
    __syncthreads();
    float acc = tb1[t];
    #pragma unroll 2
    for (int k = 0; k < DIM; k += 4) {
        float4 v = *(const float4*)&a_s[k];
        acc = fmaf(v.x, tw1[(k + 0) * DIM + t], acc);
        acc = fmaf(v.y, tw1[(k + 1) * DIM + t], acc);
        acc = fmaf(v.z, tw1[(k + 2) * DIM + t], acc);
        acc = fmaf(v.w, tw1[(k + 3) * DIM + t], acc);
    }
    h_s[t] = leakyf(acc);
    __syncthreads();
    float acc2 = tb2[t];
    #pragma unroll 2
    for (int k = 0; k < DIM; k += 4) {
        float4 v = *(const float4*)&h_s[k];
        acc2 = fmaf(v.x, tw2[(k + 0) * DIM + t], acc2);
        acc2 = fmaf(v.y, tw2[(k + 1) * DIM + t], acc2);
        acc2 = fmaf(v.z, tw2[(k + 2) * DIM + t], acc2);
        acc2 = fmaf(v.w, tw2[(k + 3) * DIM + t], acc2);
    }
    out[i * DIM + t] = acc2;
}

// ---------------- batch segment bounds ----------------
__global__ __launch_bounds__(64) void batch_starts_r8(const int* __restrict__ abatch,
                                                      int* __restrict__ starts)
{
    int t = threadIdx.x;
    if (t <= 8) {
        int lo = 0, hi = NAT;
        while (lo < hi) { int m = (lo + hi) >> 1; if (abatch[m] < t) lo = m + 1; else hi = m; }
        starts[t] = lo;
    }
}

// ---------------- wave-parallel KNN: one wave per query ----------------
__global__ __launch_bounds__(256) void knn_r8(
    const float* __restrict__ xyz, const int* __restrict__ xbatch,
    const float* __restrict__ axyz, const int* __restrict__ abatch,
    const int* __restrict__ starts,
    int* __restrict__ idx_aa, float* __restrict__ dist_aa,
    int* __restrict__ idx_xa, float* __restrict__ dist_xa)
{
    const int w = blockIdx.x * 4 + (threadIdx.x >> 6);
    if (w >= NAT + NXQ) return;
    const int l = threadIdx.x & 63;
    const bool is_aa = w < NAT;
    const int q = is_aa ? w : w - NAT;
    float qx, qy, qz; int qb;
    if (is_aa) { qx = axyz[3 * q]; qy = axyz[3 * q + 1]; qz = axyz[3 * q + 2]; qb = abatch[q]; }
    else       { qx = xyz[3 * q];  qy = xyz[3 * q + 1];  qz = xyz[3 * q + 2];  qb = xbatch[q]; }
    const int lo = starts[qb];
    const int hi = starts[qb + 1];

    float d[KCAP];
    #pragma unroll
    for (int s = 0; s < KCAP; ++s) {
        const int j = lo + s * 64 + l;
        float d2 = BIGD;
        if (j < hi && !(is_aa && j == q)) {
            float dx = qx - axyz[3 * j];
            float dy = qy - axyz[3 * j + 1];
            float dz = qz - axyz[3 * j + 2];
            d2 = dx * dx + dy * dy + dz * dz;
        }
        d[s] = d2;
    }

    unsigned mask = 0;
    unsigned long long outk = 0;
    #pragma unroll 1
    for (int it = 0; it < KNN; ++it) {
        float bd = BIGD; int bs = 0;
        #pragma unroll
        for (int s = 0; s < KCAP; ++s) {
            bool c = !((mask >> s) & 1u) && d[s] < bd;
            bd = c ? d[s] : bd;
            bs = c ? s : bs;
        }
        const int bj = lo + bs * 64 + l;
        unsigned long long mykey = ((unsigned long long)__float_as_uint(bd) << 32) | (unsigned)bj;
        unsigned long long key = mykey;
        #pragma unroll
        for (int m = 32; m >= 1; m >>= 1) {
            unsigned long long o = shfl_xor_u64(key, m);
            key = (o < key) ? o : key;
        }
        if (key == mykey) mask |= 1u << bs;
        if (l == it) outk = key;
    }

    if (l < KNN) {
        unsigned ju = (unsigned)(outk & 0xffffffffu);
        float dw = __uint_as_float((unsigned)(outk >> 32));
        int jc = (ju >= (unsigned)NAT) ? 0 : (int)ju;
        int*   ip = is_aa ? (idx_aa + q * KNN)  : (idx_xa + q * KNN);
        float* dp = is_aa ? (dist_aa + q * KNN) : (dist_xa + q * KNN);
        ip[l] = jc;
        dp[l] = dw;
    }
}

// ---------------- lin128: out[i][c] = bias[c] + src[i] @ w1[rowoff:rowoff+128, c] ----
// cols 0..256 (col 256 via shfl reduction); 8 rows per block, out stride HD.
__global__ __launch_bounds__(256) void lin128_r8(
    const float* __restrict__ src, const float* __restrict__ w1, int rowoff,
    const float* __restrict__ bias,                 // may be null
    float* __restrict__ out)
{
    const int t = threadIdx.x;
    const int i0 = blockIdx.x * 8;
    __shared__ __align__(16) float cen_s[8][DIM];
    #pragma unroll
    for (int it = 0; it < 4; ++it) {
        int lin = it * 256 + t;
        int a = lin >> 7, j = lin & 127;
        cen_s[a][j] = src[(size_t)(i0 + a) * DIM + j];
    }
    __syncthreads();

    const float* wbase = w1 + (size_t)rowoff * HD;
    float acc[8];
    {
        const float b = bias ? bias[t] : 0.0f;
        #pragma unroll
        for (int a = 0; a < 8; ++a) acc[a] = b;
    }
    #pragma unroll 2
    for (int k = 0; k < DIM; k += 4) {
        float w0 = wbase[(size_t)(k + 0) * HD + t];
        float wa = wbase[(size_t)(k + 1) * HD + t];
        float wb = wbase[(size_t)(k + 2) * HD + t];
        float wc = wbase[(size_t)(k + 3) * HD + t];
        #pragma unroll
        for (int a = 0; a < 8; ++a) {
            float4 c = *(const float4*)&cen_s[a][k];
            acc[a] = fmaf(c.x, w0, acc[a]);
            acc[a] = fmaf(c.y, wa, acc[a]);
            acc[a] = fmaf(c.z, wb, acc[a]);
            acc[a] = fmaf(c.w, wc, acc[a]);
        }
    }
    #pragma unroll
    for (int a = 0; a < 8; ++a)
        out[(size_t)(i0 + a) * HD + t] = acc[a];

    // column 256: 32 lanes per row
    {
        const int a = t >> 5, l32 = t & 31;
        float p = 0.f;
        #pragma unroll
        for (int m = 0; m < 4; ++m) {
            const int k = l32 + 32 * m;
            p = fmaf(cen_s[a][k], wbase[(size_t)k * HD + 256], p);
        }
        #pragma unroll
        for (int m = 1; m < 32; m <<= 1) p += __shfl_xor(p, m);
        if (l32 == 0) out[(size_t)(i0 + a) * HD + 256] = p + (bias ? bias[256] : 0.0f);
    }
}

// ---------------- aggregate: S[i][c] = sum_e leaky(c1[i][c] + P[idx[e]][c] + d_e*wd[c]) ----
// one atom per block, 256 threads = cols 0..255; col 256 on lanes 0..15.
__global__ __launch_bounds__(256) void aggregate_r8(
    const int* __restrict__ nidx, const float* __restrict__ ndist,
    const float* __restrict__ c1ws, const float* __restrict__ Pws,
    const float* __restrict__ w1,
    float* __restrict__ Sws)
{
    const int i = blockIdx.x;
    const int t = threadIdx.x;
    __shared__ int   eidx[KNN];
    __shared__ float edist[KNN];
    if (t < KNN) {
        eidx[t]  = nidx[i * KNN + t];
        edist[t] = ndist[i * KNN + t];
    }
    __syncthreads();

    const float c1v = c1ws[(size_t)i * HD + t];
    const float wd  = w1[(size_t)256 * HD + t];
    float s = 0.f;
    #pragma unroll
    for (int e = 0; e < KNN; ++e) {
        const float pv = Pws[(size_t)eidx[e] * HD + t];
        s += leakyf(fmaf(edist[e], wd, c1v + pv));
    }
    Sws[(size_t)i * SWS_LD + t] = s;

    // col 256
    if (t < KNN) {
        const float wt = w1[(size_t)256 * HD + 256];
        const float c1_256 = c1ws[(size_t)i * HD + 256];
        float h = leakyf(fmaf(edist[t], wt, c1_256 + Pws[(size_t)eidx[t] * HD + 256]));
        #pragma unroll
        for (int m = 1; m < 16; m <<= 1) h += __shfl_xor(h, m);
        if (t == 0) Sws[(size_t)i * SWS_LD + 256] = h;
    }
}

// ---------------- stage D: msg = S@w2 + 16*b2; GN; residual (8 atoms/block) ----------------
__global__ __launch_bounds__(256) void stage_d_r8(
    const float* __restrict__ centers,
    const float* __restrict__ Sws,
    const float* __restrict__ w2, const float* __restrict__ b2,
    const float* __restrict__ gw, const float* __restrict__ gb,
    float* __restrict__ dst)
{
    const int t = threadIdx.x;
    const int i0 = blockIdx.x * 8;
    __shared__ __align__(16) float S_s[8][260];

    #pragma unroll
    for (int it = 0; it < 3; ++it) {
        int lin = it * 256 + t;                   // 520 f32x4 slots (8 x 65)
        if (lin < 520) {
            int a = lin / 65, qd = lin - a * 65;
            *(f32x4*)&S_s[a][qd * 4] = *(const f32x4*)&Sws[(size_t)(i0 + a) * SWS_LD + qd * 4];
        }
    }
    __syncthreads();

    const int j = t & 127, abase = t >> 7;
    float macc0 = 16.0f * b2[j], macc1 = macc0, macc2 = macc0, macc3 = macc0;
    #pragma unroll 2
    for (int k = 0; k < 256; k += 4) {
        float w0 = w2[(k + 0) * DIM + j];
        float wa = w2[(k + 1) * DIM + j];
        float wb = w2[(k + 2) * DIM + j];
        float wc = w2[(k + 3) * DIM + j];
        f32x4 s0 = *(const f32x4*)&S_s[abase + 0][k];
        f32x4 s1 = *(const f32x4*)&S_s[abase + 2][k];
        f32x4 s2 = *(const f32x4*)&S_s[abase + 4][k];
        f32x4 s3 = *(const f32x4*)&S_s[abase + 6][k];
        macc0 = fmaf(s0[0], w0, macc0); macc0 = fmaf(s0[1], wa, macc0);
        macc0 = fmaf(s0[2], wb, macc0); macc0 = fmaf(s0[3], wc, macc0);
        macc1 = fmaf(s1[0], w0, macc1); macc1 = fmaf(s1[1], wa, macc1);
        macc1 = fmaf(s1[2], wb, macc1); macc1 = fmaf(s1[3], wc, macc1);
        macc2 = fmaf(s2[0], w0, macc2); macc2 = fmaf(s2[1], wa, macc2);
        macc2 = fmaf(s2[2], wb, macc2); macc2 = fmaf(s2[3], wc, macc2);
        macc3 = fmaf(s3[0], w0, macc3); macc3 = fmaf(s3[1], wa, macc3);
        macc3 = fmaf(s3[2], wb, macc3); macc3 = fmaf(s3[3], wc, macc3);
    }
    {
        const float w256 = w2[256 * DIM + j];
        macc0 = fmaf(S_s[abase + 0][256], w256, macc0);
        macc1 = fmaf(S_s[abase + 2][256], w256, macc1);
        macc2 = fmaf(S_s[abase + 4][256], w256, macc2);
        macc3 = fmaf(S_s[abase + 6][256], w256, macc3);
    }

    const float gwj = gw[j], gbj = gb[j];
    float m0 = macc0, m1 = macc1, m2 = macc2, m3 = macc3;
    #pragma unroll
    for (int m = 1; m < 64; m <<= 1) {
        m0 += __shfl_xor(m0, m); m1 += __shfl_xor(m1, m);
        m2 += __shfl_xor(m2, m); m3 += __shfl_xor(m3, m);
    }
    const float mu0 = m0 * (1.f / 64.f), mu1 = m1 * (1.f / 64.f);
    const float mu2 = m2 * (1.f / 64.f), mu3 = m3 * (1.f / 64.f);
    float d0 = macc0 - mu0, d1 = macc1 - mu1, d2 = macc2 - mu2, d3 = macc3 - mu3;
    float v0 = d0 * d0, v1 = d1 * d1, v2 = d2 * d2, v3 = d3 * d3;
    #pragma unroll
    for (int m = 1; m < 64; m <<= 1) {
        v0 += __shfl_xor(v0, m); v1 += __shfl_xor(v1, m);
        v2 += __shfl_xor(v2, m); v3 += __shfl_xor(v3, m);
    }
    v0 *= (1.f / 64.f); v1 *= (1.f / 64.f); v2 *= (1.f / 64.f); v3 *= (1.f / 64.f);
    const float y0 = fmaf(d0 * rsqrtf(v0 + GN_EPS), gwj, gbj);
    const float y1 = fmaf(d1 * rsqrtf(v1 + GN_EPS), gwj, gbj);
    const float y2 = fmaf(d2 * rsqrtf(v2 + GN_EPS), gwj, gbj);
    const float y3 = fmaf(d3 * rsqrtf(v3 + GN_EPS), gwj, gbj);
    dst[(size_t)(i0 + abase + 0) * DIM + j] = centers[(size_t)(i0 + abase + 0) * DIM + j] + leakyf(y0);
    dst[(size_t)(i0 + abase + 2) * DIM + j] = centers[(size_t)(i0 + abase + 2) * DIM + j] + leakyf(y1);
    dst[(size_t)(i0 + abase + 4) * DIM + j] = centers[(size_t)(i0 + abase + 4) * DIM + j] + leakyf(y2);
    dst[(size_t)(i0 + abase + 6) * DIM + j] = centers[(size_t)(i0 + abase + 6) * DIM + j] + leakyf(y3);
}

extern "C" void kernel_launch(void* const* d_in, const int* in_sizes, int n_in,
                              void* d_out, int out_size, void* d_ws, size_t ws_size,
                              hipStream_t stream)
{
    const size_t out_bytes = (size_t)out_size * sizeof(float);
    if (n_in != 21) { (void)hipMemsetAsync(d_out, 0x43, out_bytes, stream); return; }

    const size_t n_atoms_f = (size_t)NAT * DIM;
    const size_t n_emb_f   = (size_t)NXQ * DIM;
    const size_t n_c1_f    = (size_t)NXQ * HD;
    const size_t n_P_f     = (size_t)NAT * HD;
    const size_t n_S_f     = (size_t)NXQ * SWS_LD;
    const size_t floats_needed = n_atoms_f * 2 + n_emb_f
        + (size_t)NAT * KNN * 2 + (size_t)NXQ * KNN * 2
        + n_c1_f + n_P_f + n_S_f + 16;
    if (ws_size < floats_needed * 4 + 64) {
        (void)hipMemsetAsync(d_out, 0x41, out_bytes, stream);
        return;
    }

    const float* xyz    = (const float*)d_in[0];
    const float* axyz   = (const float*)d_in[1];
    const float* af     = (const float*)d_in[2];
    const int*   xbatch = (const int*)d_in[3];
    const int*   abatch = (const int*)d_in[4];
    const float* tw1    = (const float*)d_in[5];
    const float* tb1    = (const float*)d_in[6];
    const float* tw2    = (const float*)d_in[7];
    const float* tb2    = (const float*)d_in[8];
    const float* aa_w1  = (const float*)d_in[9];
    const float* aa_b1  = (const float*)d_in[10];
    const float* aa_w2  = (const float*)d_in[11];
    const float* aa_b2  = (const float*)d_in[12];
    const float* aa_gw  = (const float*)d_in[13];
    const float* aa_gb  = (const float*)d_in[14];
    const float* ae_w1  = (const float*)d_in[15];
    const float* ae_b1  = (const float*)d_in[16];
    const float* ae_w2  = (const float*)d_in[17];
    const float* ae_b2  = (const float*)d_in[18];
    const float* ae_gw  = (const float*)d_in[19];
    const float* ae_gb  = (const float*)d_in[20];

    float* fp      = (float*)d_ws;
    float* atoms_a = fp;                 fp += n_atoms_f;
    float* atoms_b = fp;                 fp += n_atoms_f;
    float* emb     = fp;                 fp += n_emb_f;
    int*   idx_aa  = (int*)fp;           fp += (size_t)NAT * KNN;
    float* dist_aa = fp;                 fp += (size_t)NAT * KNN;
    int*   idx_xa  = (int*)fp;           fp += (size_t)NXQ * KNN;
    float* dist_xa = fp;                 fp += (size_t)NXQ * KNN;
    float* c1ws    = fp;                 fp += n_c1_f;
    float* Pws     = fp;                 fp += n_P_f;
    float* Sws     = fp;                 fp += n_S_f;
    int*   bstarts = (int*)fp;           fp += 16;

    const int NOUT = NXQ * DIM;

    fill_f32_r8<<<(NOUT + 255) / 256, 256, 0, stream>>>(emb, NOUT, 1.0f);
    feat_transform_r8<<<NAT, 128, 0, stream>>>(af, tw1, tb1, tw2, tb2, atoms_a);
    batch_starts_r8<<<1, 64, 0, stream>>>(abatch, bstarts);
    knn_r8<<<(NAT + NXQ + 3) / 4, 256, 0, stream>>>(
        xyz, xbatch, axyz, abatch, bstarts, idx_aa, dist_aa, idx_xa, dist_xa);

    // ---- atom-atom layers ----
    float* cur = atoms_a;
    float* nxt = atoms_b;
    for (int i = 0; i < NLAYER; ++i) {
        const float* w1p = aa_w1 + (size_t)i * HD * HD;
        lin128_r8<<<NAT / 8, 256, 0, stream>>>(cur, w1p, 0, aa_b1 + (size_t)i * HD, c1ws);
        lin128_r8<<<NAT / 8, 256, 0, stream>>>(cur, w1p, 128, nullptr, Pws);
        aggregate_r8<<<NAT, 256, 0, stream>>>(idx_aa, dist_aa, c1ws, Pws, w1p, Sws);
        stage_d_r8<<<NAT / 8, 256, 0, stream>>>(
            cur, Sws,
            aa_w2 + (size_t)i * HD * DIM, aa_b2 + (size_t)i * DIM,
            aa_gw + (size_t)i * DIM, aa_gb + (size_t)i * DIM, nxt);
        float* tmp = cur; cur = nxt; nxt = tmp;
    }
    const float* atoms_final = cur;

    // ---- xyz-atom layers ----
    for (int i = 0; i < NLAYER; ++i) {
        const float* w1p = ae_w1 + (size_t)i * HD * HD;
        lin128_r8<<<NXQ / 8, 256, 0, stream>>>(emb, w1p, 0, ae_b1 + (size_t)i * HD, c1ws);
        lin128_r8<<<NAT / 8, 256, 0, stream>>>(atoms_final, w1p, 128, nullptr, Pws);
        aggregate_r8<<<NXQ, 256, 0, stream>>>(idx_xa, dist_xa, c1ws, Pws, w1p, Sws);
        float* dsti = (i == NLAYER - 1) ? (float*)d_out : emb;
        stage_d_r8<<<NXQ / 8, 256, 0, stream>>>(
            emb, Sws,
            ae_w2 + (size_t)i * HD * DIM, ae_b2 + (size_t)i * DIM,
            ae_gw + (size_t)i * DIM, ae_gb + (size_t)i * DIM, dsti);
    }
}

// Round 9
// 432.633 us; speedup vs baseline: 2.8971x; 1.0725x over previous
//
#include <hip/hip_runtime.h>
#include <hip/hip_bf16.h>

#define NAT 4096
#define NXQ 8192
#define DIM 128
#define KNN 16
#define HD  257   // 2*DIM+1
#define NLAYER 3
#define SLOPE 0.2f
#define GN_EPS 1e-5f
#define BIGD 1e30f
#define KCAP 16

typedef __attribute__((ext_vector_type(4))) float f32x4;

__device__ __forceinline__ float leakyf(float z) { return z >= 0.0f ? z : SLOPE * z; }
__device__ __forceinline__ unsigned long long shfl_xor_u64(unsigned long long v, int m) {
    int lo = __shfl_xor((int)(v & 0xffffffffu), m);
    int hi = __shfl_xor((int)(v >> 32), m);
    return ((unsigned long long)(unsigned)hi << 32) | (unsigned)lo;
}

// ---------------- fill ----------------
__global__ void fill_f32_r9(float* __restrict__ p, int n, float v)
{
    int i = blockIdx.x * 256 + threadIdx.x;
    if (i < n) p[i] = v;
}

// ---------------- initial per-atom feature MLP ----------------
__global__ __launch_bounds__(128) void feat_transform_r9(
    const float* __restrict__ af,
    const float* __restrict__ tw1, const float* __restrict__ tb1,
    const float* __restrict__ tw2, const float* __restrict__ tb2,
    float* __restrict__ out)
{
    const int i = blockIdx.x;
    const int t = threadIdx.x;
    __shared__ __align__(16) float a_s[DIM];
    __shared__ __align__(16) float h_s[DIM];
    a_s[t] = af[i * DIM + t];
    __syncthreads();
    float acc = tb1[t];
    #pragma unroll 2
    for (int k = 0; k < DIM; k += 4) {
        float4 v = *(const float4*)&a_s[k];
        acc = fmaf(v.x, tw1[(k + 0) * DIM + t], acc);
        acc = fmaf(v.y, tw1[(k + 1) * DIM + t], acc);
        acc = fmaf(v.z, tw1[(k + 2) * DIM + t], acc);
        acc = fmaf(v.w, tw1[(k + 3) * DIM + t], acc);
    }
    h_s[t] = leakyf(acc);
    __syncthreads();
    float acc2 = tb2[t];
    #pragma unroll 2
    for (int k = 0; k < DIM; k += 4) {
        float4 v = *(const float4*)&h_s[k];
        acc2 = fmaf(v.x, tw2[(k + 0) * DIM + t], acc2);
        acc2 = fmaf(v.y, tw2[(k + 1) * DIM + t], acc2);
        acc2 = fmaf(v.z, tw2[(k + 2) * DIM + t], acc2);
        acc2 = fmaf(v.w, tw2[(k + 3) * DIM + t], acc2);
    }
    out[i * DIM + t] = acc2;
}

// ---------------- batch segment bounds ----------------
__global__ __launch_bounds__(64) void batch_starts_r9(const int* __restrict__ abatch,
                                                      int* __restrict__ starts)
{
    int t = threadIdx.x;
    if (t <= 8) {
        int lo = 0, hi = NAT;
        while (lo < hi) { int m = (lo + hi) >> 1; if (abatch[m] < t) lo = m + 1; else hi = m; }
        starts[t] = lo;
    }
}

// ---------------- wave-parallel KNN: one wave per query ----------------
__global__ __launch_bounds__(256) void knn_r9(
    const float* __restrict__ xyz, const int* __restrict__ xbatch,
    const float* __restrict__ axyz, const int* __restrict__ abatch,
    const int* __restrict__ starts,
    int* __restrict__ idx_aa, float* __restrict__ dist_aa,
    int* __restrict__ idx_xa, float* __restrict__ dist_xa)
{
    const int w = blockIdx.x * 4 + (threadIdx.x >> 6);
    if (w >= NAT + NXQ) return;
    const int l = threadIdx.x & 63;
    const bool is_aa = w < NAT;
    const int q = is_aa ? w : w - NAT;
    float qx, qy, qz; int qb;
    if (is_aa) { qx = axyz[3 * q]; qy = axyz[3 * q + 1]; qz = axyz[3 * q + 2]; qb = abatch[q]; }
    else       { qx = xyz[3 * q];  qy = xyz[3 * q + 1];  qz = xyz[3 * q + 2];  qb = xbatch[q]; }
    const int lo = starts[qb];
    const int hi = starts[qb + 1];

    float d[KCAP];
    #pragma unroll
    for (int s = 0; s < KCAP; ++s) {
        const int j = lo + s * 64 + l;
        float d2 = BIGD;
        if (j < hi && !(is_aa && j == q)) {
            float dx = qx - axyz[3 * j];
            float dy = qy - axyz[3 * j + 1];
            float dz = qz - axyz[3 * j + 2];
            d2 = dx * dx + dy * dy + dz * dz;
        }
        d[s] = d2;
    }

    unsigned mask = 0;
    unsigned long long outk = 0;
    #pragma unroll 1
    for (int it = 0; it < KNN; ++it) {
        float bd = BIGD; int bs = 0;
        #pragma unroll
        for (int s = 0; s < KCAP; ++s) {
            bool c = !((mask >> s) & 1u) && d[s] < bd;
            bd = c ? d[s] : bd;
            bs = c ? s : bs;
        }
        const int bj = lo + bs * 64 + l;
        unsigned long long mykey = ((unsigned long long)__float_as_uint(bd) << 32) | (unsigned)bj;
        unsigned long long key = mykey;
        #pragma unroll
        for (int m = 32; m >= 1; m >>= 1) {
            unsigned long long o = shfl_xor_u64(key, m);
            key = (o < key) ? o : key;
        }
        if (key == mykey) mask |= 1u << bs;
        if (l == it) outk = key;
    }

    if (l < KNN) {
        unsigned ju = (unsigned)(outk & 0xffffffffu);
        float dw = __uint_as_float((unsigned)(outk >> 32));
        int jc = (ju >= (unsigned)NAT) ? 0 : (int)ju;
        int*   ip = is_aa ? (idx_aa + q * KNN)  : (idx_xa + q * KNN);
        float* dp = is_aa ? (dist_aa + q * KNN) : (dist_xa + q * KNN);
        ip[l] = jc;
        dp[l] = dw;
    }
}

// ---------------- P = src @ w1[128:256, :] (cols 0..256), 8 rows/block ----------------
__global__ __launch_bounds__(256) void lin128_r9(
    const float* __restrict__ src, const float* __restrict__ w1,
    float* __restrict__ out)
{
    const int t = threadIdx.x;
    const int i0 = blockIdx.x * 8;
    __shared__ __align__(16) float cen_s[8][DIM];
    #pragma unroll
    for (int it = 0; it < 4; ++it) {
        int lin = it * 256 + t;
        int a = lin >> 7, j = lin & 127;
        cen_s[a][j] = src[(size_t)(i0 + a) * DIM + j];
    }
    __syncthreads();

    const float* wbase = w1 + (size_t)128 * HD;
    float acc[8];
    #pragma unroll
    for (int a = 0; a < 8; ++a) acc[a] = 0.0f;
    #pragma unroll 2
    for (int k = 0; k < DIM; k += 4) {
        float w0 = wbase[(size_t)(k + 0) * HD + t];
        float wa = wbase[(size_t)(k + 1) * HD + t];
        float wb = wbase[(size_t)(k + 2) * HD + t];
        float wc = wbase[(size_t)(k + 3) * HD + t];
        #pragma unroll
        for (int a = 0; a < 8; ++a) {
            float4 c = *(const float4*)&cen_s[a][k];
            acc[a] = fmaf(c.x, w0, acc[a]);
            acc[a] = fmaf(c.y, wa, acc[a]);
            acc[a] = fmaf(c.z, wb, acc[a]);
            acc[a] = fmaf(c.w, wc, acc[a]);
        }
    }
    #pragma unroll
    for (int a = 0; a < 8; ++a)
        out[(size_t)(i0 + a) * HD + t] = acc[a];

    // column 256: 32 lanes per row
    {
        const int a = t >> 5, l32 = t & 31;
        float p = 0.f;
        #pragma unroll
        for (int m = 0; m < 4; ++m) {
            const int k = l32 + 32 * m;
            p = fmaf(cen_s[a][k], wbase[(size_t)k * HD + 256], p);
        }
        #pragma unroll
        for (int m = 1; m < 32; m <<= 1) p += __shfl_xor(p, m);
        if (l32 == 0) out[(size_t)(i0 + a) * HD + 256] = p;
    }
}

// ---------------- fused layer: c1 (regs) + aggregate (gather P) + S@w2 + GN + residual ----
// 8 atoms per block, 256 threads. dst may alias centers (own rows only).
__global__ __launch_bounds__(256) void layer_fused_r9(
    const float* __restrict__ centers,
    const float* __restrict__ Pws,
    const int* __restrict__ nidx, const float* __restrict__ ndist,
    const float* __restrict__ w1, const float* __restrict__ b1,
    const float* __restrict__ w2, const float* __restrict__ b2,
    const float* __restrict__ gw, const float* __restrict__ gb,
    float* __restrict__ dst)
{
    const int t = threadIdx.x;
    const int i0 = blockIdx.x * 8;

    __shared__ __align__(16) float cen_s[8][DIM];
    __shared__ __align__(16) float S_s[8][260];
    __shared__ int   eidx_s[8][KNN];
    __shared__ float edist_s[8][KNN];
    __shared__ float c1_256_s[8];

    // ---- stage in ----
    #pragma unroll
    for (int it = 0; it < 4; ++it) {
        int lin = it * 256 + t;
        int a = lin >> 7, j = lin & 127;
        cen_s[a][j] = centers[(size_t)(i0 + a) * DIM + j];
    }
    if (t < 128) {
        int a = t >> 4, e = t & 15;
        eidx_s[a][e]  = nidx[(size_t)(i0 + a) * KNN + e];
        edist_s[a][e] = ndist[(size_t)(i0 + a) * KNN + e];
    }
    __syncthreads();

    // ---- c1[a][t] in registers ----
    float c1a[8];
    {
        const float b = b1[t];
        #pragma unroll
        for (int a = 0; a < 8; ++a) c1a[a] = b;
    }
    #pragma unroll 2
    for (int k = 0; k < DIM; k += 4) {
        float w0 = w1[(size_t)(k + 0) * HD + t];
        float wa = w1[(size_t)(k + 1) * HD + t];
        float wb = w1[(size_t)(k + 2) * HD + t];
        float wc = w1[(size_t)(k + 3) * HD + t];
        #pragma unroll
        for (int a = 0; a < 8; ++a) {
            float4 c = *(const float4*)&cen_s[a][k];
            c1a[a] = fmaf(c.x, w0, c1a[a]);
            c1a[a] = fmaf(c.y, wa, c1a[a]);
            c1a[a] = fmaf(c.z, wb, c1a[a]);
            c1a[a] = fmaf(c.w, wc, c1a[a]);
        }
    }
    // c1 col 256: 32 lanes per atom
    {
        const int a = t >> 5, l32 = t & 31;
        float p = 0.f;
        #pragma unroll
        for (int m = 0; m < 4; ++m) {
            const int k = l32 + 32 * m;
            p = fmaf(cen_s[a][k], w1[(size_t)k * HD + 256], p);
        }
        #pragma unroll
        for (int m = 1; m < 32; m <<= 1) p += __shfl_xor(p, m);
        if (l32 == 0) c1_256_s[a] = p + b1[256];
    }
    __syncthreads();

    // ---- aggregate: S[a][t] = sum_e leaky(c1[a][t] + P[idx][t] + d*wd[t]) ----
    {
        const float wd = w1[(size_t)256 * HD + t];
        float sa[8];
        #pragma unroll
        for (int a = 0; a < 8; ++a) sa[a] = 0.f;
        #pragma unroll 4
        for (int e = 0; e < KNN; ++e) {
            float pv[8];
            #pragma unroll
            for (int a = 0; a < 8; ++a)
                pv[a] = Pws[(size_t)eidx_s[a][e] * HD + t];
            #pragma unroll
            for (int a = 0; a < 8; ++a)
                sa[a] += leakyf(fmaf(edist_s[a][e], wd, c1a[a] + pv[a]));
        }
        #pragma unroll
        for (int a = 0; a < 8; ++a) S_s[a][t] = sa[a];
    }
    // col 256: threads 0..127, a = t>>4, e = t&15
    if (t < 128) {
        const int a = t >> 4, e = t & 15;
        const float wt = w1[(size_t)256 * HD + 256];
        float h = leakyf(fmaf(edist_s[a][e], wt,
                              c1_256_s[a] + Pws[(size_t)eidx_s[a][e] * HD + 256]));
        #pragma unroll
        for (int m = 1; m < 16; m <<= 1) h += __shfl_xor(h, m);
        if (e == 0) S_s[a][256] = h;
    }
    __syncthreads();

    // ---- stage D: msg = S@w2 + 16*b2; GN; residual ----
    const int j = t & 127, abase = t >> 7;
    float macc0 = 16.0f * b2[j], macc1 = macc0, macc2 = macc0, macc3 = macc0;
    #pragma unroll 2
    for (int k = 0; k < 256; k += 4) {
        float w0 = w2[(k + 0) * DIM + j];
        float wa = w2[(k + 1) * DIM + j];
        float wb = w2[(k + 2) * DIM + j];
        float wc = w2[(k + 3) * DIM + j];
        f32x4 s0 = *(const f32x4*)&S_s[abase + 0][k];
        f32x4 s1 = *(const f32x4*)&S_s[abase + 2][k];
        f32x4 s2 = *(const f32x4*)&S_s[abase + 4][k];
        f32x4 s3 = *(const f32x4*)&S_s[abase + 6][k];
        macc0 = fmaf(s0[0], w0, macc0); macc0 = fmaf(s0[1], wa, macc0);
        macc0 = fmaf(s0[2], wb, macc0); macc0 = fmaf(s0[3], wc, macc0);
        macc1 = fmaf(s1[0], w0, macc1); macc1 = fmaf(s1[1], wa, macc1);
        macc1 = fmaf(s1[2], wb, macc1); macc1 = fmaf(s1[3], wc, macc1);
        macc2 = fmaf(s2[0], w0, macc2); macc2 = fmaf(s2[1], wa, macc2);
        macc2 = fmaf(s2[2], wb, macc2); macc2 = fmaf(s2[3], wc, macc2);
        macc3 = fmaf(s3[0], w0, macc3); macc3 = fmaf(s3[1], wa, macc3);
        macc3 = fmaf(s3[2], wb, macc3); macc3 = fmaf(s3[3], wc, macc3);
    }
    {
        const float w256 = w2[256 * DIM + j];
        macc0 = fmaf(S_s[abase + 0][256], w256, macc0);
        macc1 = fmaf(S_s[abase + 2][256], w256, macc1);
        macc2 = fmaf(S_s[abase + 4][256], w256, macc2);
        macc3 = fmaf(S_s[abase + 6][256], w256, macc3);
    }

    const float gwj = gw[j], gbj = gb[j];
    float m0 = macc0, m1 = macc1, m2 = macc2, m3 = macc3;
    #pragma unroll
    for (int m = 1; m < 64; m <<= 1) {
        m0 += __shfl_xor(m0, m); m1 += __shfl_xor(m1, m);
        m2 += __shfl_xor(m2, m); m3 += __shfl_xor(m3, m);
    }
    const float mu0 = m0 * (1.f / 64.f), mu1 = m1 * (1.f / 64.f);
    const float mu2 = m2 * (1.f / 64.f), mu3 = m3 * (1.f / 64.f);
    float d0 = macc0 - mu0, d1 = macc1 - mu1, d2 = macc2 - mu2, d3 = macc3 - mu3;
    float v0 = d0 * d0, v1 = d1 * d1, v2 = d2 * d2, v3 = d3 * d3;
    #pragma unroll
    for (int m = 1; m < 64; m <<= 1) {
        v0 += __shfl_xor(v0, m); v1 += __shfl_xor(v1, m);
        v2 += __shfl_xor(v2, m); v3 += __shfl_xor(v3, m);
    }
    v0 *= (1.f / 64.f); v1 *= (1.f / 64.f); v2 *= (1.f / 64.f); v3 *= (1.f / 64.f);
    const float y0 = fmaf(d0 * rsqrtf(v0 + GN_EPS), gwj, gbj);
    const float y1 = fmaf(d1 * rsqrtf(v1 + GN_EPS), gwj, gbj);
    const float y2 = fmaf(d2 * rsqrtf(v2 + GN_EPS), gwj, gbj);
    const float y3 = fmaf(d3 * rsqrtf(v3 + GN_EPS), gwj, gbj);
    dst[(size_t)(i0 + abase + 0) * DIM + j] = cen_s[abase + 0][j] + leakyf(y0);
    dst[(size_t)(i0 + abase + 2) * DIM + j] = cen_s[abase + 2][j] + leakyf(y1);
    dst[(size_t)(i0 + abase + 4) * DIM + j] = cen_s[abase + 4][j] + leakyf(y2);
    dst[(size_t)(i0 + abase + 6) * DIM + j] = cen_s[abase + 6][j] + leakyf(y3);
}

extern "C" void kernel_launch(void* const* d_in, const int* in_sizes, int n_in,
                              void* d_out, int out_size, void* d_ws, size_t ws_size,
                              hipStream_t stream)
{
    const size_t out_bytes = (size_t)out_size * sizeof(float);
    if (n_in != 21) { (void)hipMemsetAsync(d_out, 0x43, out_bytes, stream); return; }

    const size_t n_atoms_f = (size_t)NAT * DIM;
    const size_t n_emb_f   = (size_t)NXQ * DIM;
    const size_t n_P_f     = (size_t)NAT * HD;
    const size_t floats_needed = n_atoms_f * 2 + n_emb_f
        + (size_t)NAT * KNN * 2 + (size_t)NXQ * KNN * 2 + n_P_f + 16;
    if (ws_size < floats_needed * 4 + 64) {
        (void)hipMemsetAsync(d_out, 0x41, out_bytes, stream);
        return;
    }

    const float* xyz    = (const float*)d_in[0];
    const float* axyz   = (const float*)d_in[1];
    const float* af     = (const float*)d_in[2];
    const int*   xbatch = (const int*)d_in[3];
    const int*   abatch = (const int*)d_in[4];
    const float* tw1    = (const float*)d_in[5];
    const float* tb1    = (const float*)d_in[6];
    const float* tw2    = (const float*)d_in[7];
    const float* tb2    = (const float*)d_in[8];
    const float* aa_w1  = (const float*)d_in[9];
    const float* aa_b1  = (const float*)d_in[10];
    const float* aa_w2  = (const float*)d_in[11];
    const float* aa_b2  = (const float*)d_in[12];
    const float* aa_gw  = (const float*)d_in[13];
    const float* aa_gb  = (const float*)d_in[14];
    const float* ae_w1  = (const float*)d_in[15];
    const float* ae_b1  = (const float*)d_in[16];
    const float* ae_w2  = (const float*)d_in[17];
    const float* ae_b2  = (const float*)d_in[18];
    const float* ae_gw  = (const float*)d_in[19];
    const float* ae_gb  = (const float*)d_in[20];

    float* fp      = (float*)d_ws;
    float* atoms_a = fp;                 fp += n_atoms_f;
    float* atoms_b = fp;                 fp += n_atoms_f;
    float* emb     = fp;                 fp += n_emb_f;
    int*   idx_aa  = (int*)fp;           fp += (size_t)NAT * KNN;
    float* dist_aa = fp;                 fp += (size_t)NAT * KNN;
    int*   idx_xa  = (int*)fp;           fp += (size_t)NXQ * KNN;
    float* dist_xa = fp;                 fp += (size_t)NXQ * KNN;
    float* Pws     = fp;                 fp += n_P_f;
    int*   bstarts = (int*)fp;           fp += 16;

    const int NOUT = NXQ * DIM;

    fill_f32_r9<<<(NOUT + 255) / 256, 256, 0, stream>>>(emb, NOUT, 1.0f);
    feat_transform_r9<<<NAT, 128, 0, stream>>>(af, tw1, tb1, tw2, tb2, atoms_a);
    batch_starts_r9<<<1, 64, 0, stream>>>(abatch, bstarts);
    knn_r9<<<(NAT + NXQ + 3) / 4, 256, 0, stream>>>(
        xyz, xbatch, axyz, abatch, bstarts, idx_aa, dist_aa, idx_xa, dist_xa);

    // ---- atom-atom layers ----
    float* cur = atoms_a;
    float* nxt = atoms_b;
    for (int i = 0; i < NLAYER; ++i) {
        const float* w1p = aa_w1 + (size_t)i * HD * HD;
        lin128_r9<<<NAT / 8, 256, 0, stream>>>(cur, w1p, Pws);
        layer_fused_r9<<<NAT / 8, 256, 0, stream>>>(
            cur, Pws, idx_aa, dist_aa,
            w1p, aa_b1 + (size_t)i * HD,
            aa_w2 + (size_t)i * HD * DIM, aa_b2 + (size_t)i * DIM,
            aa_gw + (size_t)i * DIM, aa_gb + (size_t)i * DIM, nxt);
        float* tmp = cur; cur = nxt; nxt = tmp;
    }
    const float* atoms_final = cur;

    // ---- xyz-atom layers (emb updated in place; last layer writes d_out) ----
    for (int i = 0; i < NLAYER; ++i) {
        const float* w1p = ae_w1 + (size_t)i * HD * HD;
        lin128_r9<<<NAT / 8, 256, 0, stream>>>(atoms_final, w1p, Pws);
        float* dsti = (i == NLAYER - 1) ? (float*)d_out : emb;
        layer_fused_r9<<<NXQ / 8, 256, 0, stream>>>(
            emb, Pws, idx_xa, dist_xa,
            w1p, ae_b1 + (size_t)i * HD,
            ae_w2 + (size_t)i * HD * DIM, ae_b2 + (size_t)i * DIM,
            ae_gw + (size_t)i * DIM, ae_gb + (size_t)i * DIM, dsti);
    }
}

// Round 11
// 417.263 us; speedup vs baseline: 3.0039x; 1.0368x over previous
//
#include <hip/hip_runtime.h>
#include <hip/hip_bf16.h>

#define NAT 4096
#define NXQ 8192
#define DIM 128
#define KNN 16
#define HD  257   // 2*DIM+1
#define NLAYER 3
#define SLOPE 0.2f
#define GN_EPS 1e-5f
#define BIGD 1e30f

typedef __attribute__((ext_vector_type(4))) float f32x4;

__device__ __forceinline__ float leakyf(float z) { return z >= 0.0f ? z : SLOPE * z; }
__device__ __forceinline__ unsigned long long shfl_xor_u64(unsigned long long v, int m) {
    int lo = __shfl_xor((int)(v & 0xffffffffu), m);
    int hi = __shfl_xor((int)(v >> 32), m);
    return ((unsigned long long)(unsigned)hi << 32) | (unsigned)lo;
}

// ---------------- fill ----------------
__global__ void fill_f32_r11(float* __restrict__ p, int n, float v)
{
    int i = blockIdx.x * 256 + threadIdx.x;
    if (i < n) p[i] = v;
}

// ---------------- initial per-atom feature MLP ----------------
__global__ __launch_bounds__(128) void feat_transform_r11(
    const float* __restrict__ af,
    const float* __restrict__ tw1, const float* __restrict__ tb1,
    const float* __restrict__ tw2, const float* __restrict__ tb2,
    float* __restrict__ out)
{
    const int i = blockIdx.x;
    const int t = threadIdx.x;
    __shared__ __align__(16) float a_s[DIM];
    __shared__ __align__(16) float h_s[DIM];
    a_s[t] = af[i * DIM + t];
    __syncthreads();
    float acc = tb1[t];
    #pragma unroll 2
    for (int k = 0; k < DIM; k += 4) {
        float4 v = *(const float4*)&a_s[k];
        acc = fmaf(v.x, tw1[(k + 0) * DIM + t], acc);
        acc = fmaf(v.y, tw1[(k + 1) * DIM + t], acc);
        acc = fmaf(v.z, tw1[(k + 2) * DIM + t], acc);
        acc = fmaf(v.w, tw1[(k + 3) * DIM + t], acc);
    }
    h_s[t] = leakyf(acc);
    __syncthreads();
    float acc2 = tb2[t];
    #pragma unroll 2
    for (int k = 0; k < DIM; k += 4) {
        float4 v = *(const float4*)&h_s[k];
        acc2 = fmaf(v.x, tw2[(k + 0) * DIM + t], acc2);
        acc2 = fmaf(v.y, tw2[(k + 1) * DIM + t], acc2);
        acc2 = fmaf(v.z, tw2[(k + 2) * DIM + t], acc2);
        acc2 = fmaf(v.w, tw2[(k + 3) * DIM + t], acc2);
    }
    out[i * DIM + t] = acc2;
}

// ---------------- batch segment bounds ----------------
__global__ __launch_bounds__(64) void batch_starts_r11(const int* __restrict__ abatch,
                                                       int* __restrict__ starts)
{
    int t = threadIdx.x;
    if (t <= 8) {
        int lo = 0, hi = NAT;
        while (lo < hi) { int m = (lo + hi) >> 1; if (abatch[m] < t) lo = m + 1; else hi = m; }
        starts[t] = lo;
    }
}

// ---------------- KNN selection body, CAP slots per lane ----------------
template<int CAP>
__device__ __forceinline__ unsigned long long knn_select(
    const float* __restrict__ axyz, int lo, int hi, int l, int self,
    float qx, float qy, float qz)
{
    float d[CAP];
    #pragma unroll
    for (int s = 0; s < CAP; ++s) {
        const int j = lo + s * 64 + l;
        float d2 = BIGD;
        if (j < hi && j != self) {
            float dx = qx - axyz[3 * j];
            float dy = qy - axyz[3 * j + 1];
            float dz = qz - axyz[3 * j + 2];
            d2 = dx * dx + dy * dy + dz * dz;
        }
        d[s] = d2;
    }

    unsigned mask = 0;
    unsigned long long outk = 0;
    #pragma unroll 1
    for (int it = 0; it < KNN; ++it) {
        float bd = BIGD; int bs = 0;
        #pragma unroll
        for (int s = 0; s < CAP; ++s) {
            bool c = !((mask >> s) & 1u) && d[s] < bd;
            bd = c ? d[s] : bd;
            bs = c ? s : bs;
        }
        const int bj = lo + bs * 64 + l;
        unsigned long long mykey = ((unsigned long long)__float_as_uint(bd) << 32) | (unsigned)bj;
        unsigned long long key = mykey;
        #pragma unroll
        for (int m = 32; m >= 1; m >>= 1) {
            unsigned long long o = shfl_xor_u64(key, m);
            key = (o < key) ? o : key;
        }
        if (key == mykey) mask |= 1u << bs;
        if (l == it) outk = key;
    }
    return outk;
}

// ---------------- wave-parallel KNN: one wave per query ----------------
__global__ __launch_bounds__(256) void knn_r11(
    const float* __restrict__ xyz, const int* __restrict__ xbatch,
    const float* __restrict__ axyz, const int* __restrict__ abatch,
    const int* __restrict__ starts,
    int* __restrict__ idx_aa, float* __restrict__ dist_aa,
    int* __restrict__ idx_xa, float* __restrict__ dist_xa)
{
    const int w = blockIdx.x * 4 + (threadIdx.x >> 6);
    if (w >= NAT + NXQ) return;
    const int l = threadIdx.x & 63;
    const bool is_aa = w < NAT;
    const int q = is_aa ? w : w - NAT;
    float qx, qy, qz; int qb;
    if (is_aa) { qx = axyz[3 * q]; qy = axyz[3 * q + 1]; qz = axyz[3 * q + 2]; qb = abatch[q]; }
    else       { qx = xyz[3 * q];  qy = xyz[3 * q + 1];  qz = xyz[3 * q + 2];  qb = xbatch[q]; }
    const int lo = starts[qb];
    const int hi = starts[qb + 1];
    const int self = is_aa ? q : -1;

    const int smax = (hi - lo + 63) >> 6;   // wave-uniform
    unsigned long long outk;
    if (smax <= 10) outk = knn_select<10>(axyz, lo, hi, l, self, qx, qy, qz);
    else            outk = knn_select<16>(axyz, lo, hi, l, self, qx, qy, qz);

    if (l < KNN) {
        unsigned ju = (unsigned)(outk & 0xffffffffu);
        float dw = __uint_as_float((unsigned)(outk >> 32));
        int jc = (ju >= (unsigned)NAT) ? 0 : (int)ju;
        int*   ip = is_aa ? (idx_aa + q * KNN)  : (idx_xa + q * KNN);
        float* dp = is_aa ? (dist_aa + q * KNN) : (dist_xa + q * KNN);
        ip[l] = jc;
        dp[l] = dw;
    }
}

// ---------------- P = src @ w1[128:256, :] (cols 0..256), 8 rows/block, 512 thr ----
__global__ __launch_bounds__(512) void lin128_r11(
    const float* __restrict__ src, const float* __restrict__ w1,
    float* __restrict__ out)
{
    const int t = threadIdx.x;
    const int i0 = blockIdx.x * 8;
    __shared__ __align__(16) float cen_s[8][DIM];
    #pragma unroll
    for (int it = 0; it < 2; ++it) {
        int lin = it * 512 + t;
        int a = lin >> 7, j = lin & 127;
        cen_s[a][j] = src[(size_t)(i0 + a) * DIM + j];
    }
    __syncthreads();

    const float* wbase = w1 + (size_t)128 * HD;
    const int j = t & 255, tg = t >> 8;      // rows 4*tg .. 4*tg+3
    float acc[4];
    #pragma unroll
    for (int r = 0; r < 4; ++r) acc[r] = 0.0f;
    #pragma unroll 2
    for (int k = 0; k < DIM; k += 4) {
        float w0 = wbase[(size_t)(k + 0) * HD + j];
        float wa = wbase[(size_t)(k + 1) * HD + j];
        float wb = wbase[(size_t)(k + 2) * HD + j];
        float wc = wbase[(size_t)(k + 3) * HD + j];
        #pragma unroll
        for (int r = 0; r < 4; ++r) {
            float4 c = *(const float4*)&cen_s[4 * tg + r][k];
            acc[r] = fmaf(c.x, w0, acc[r]);
            acc[r] = fmaf(c.y, wa, acc[r]);
            acc[r] = fmaf(c.z, wb, acc[r]);
            acc[r] = fmaf(c.w, wc, acc[r]);
        }
    }
    #pragma unroll
    for (int r = 0; r < 4; ++r)
        out[(size_t)(i0 + 4 * tg + r) * HD + j] = acc[r];

    // column 256: 32 lanes per row
    if (t < 256) {
        const int a = t >> 5, l32 = t & 31;
        float p = 0.f;
        #pragma unroll
        for (int m = 0; m < 4; ++m) {
            const int k = l32 + 32 * m;
            p = fmaf(cen_s[a][k], wbase[(size_t)k * HD + 256], p);
        }
        #pragma unroll
        for (int m = 1; m < 32; m <<= 1) p += __shfl_xor(p, m);
        if (l32 == 0) out[(size_t)(i0 + a) * HD + 256] = p;
    }
}

// ---------------- fused layer, 8 atoms/block, 512 threads ----------------
// c1 in regs (4 atoms/thread) -> aggregate (gather P) -> S@w2 -> GN -> residual.
// dst may alias centers (block reads own rows before writing).
__global__ __launch_bounds__(512) void layer_fused_r11(
    const float* __restrict__ centers,
    const float* __restrict__ Pws,
    const int* __restrict__ nidx, const float* __restrict__ ndist,
    const float* __restrict__ w1, const float* __restrict__ b1,
    const float* __restrict__ w2, const float* __restrict__ b2,
    const float* __restrict__ gw, const float* __restrict__ gb,
    float* __restrict__ dst)
{
    const int t = threadIdx.x;
    const int i0 = blockIdx.x * 8;

    __shared__ __align__(16) float cen_s[8][DIM];
    __shared__ __align__(16) float S_s[8][260];
    __shared__ int   eidx_s[8][KNN];
    __shared__ float edist_s[8][KNN];
    __shared__ float c1_256_s[8];

    // ---- stage in ----
    #pragma unroll
    for (int it = 0; it < 2; ++it) {
        int lin = it * 512 + t;
        int a = lin >> 7, j = lin & 127;
        cen_s[a][j] = centers[(size_t)(i0 + a) * DIM + j];
    }
    if (t < 128) {
        int a = t >> 4, e = t & 15;
        eidx_s[a][e]  = nidx[(size_t)(i0 + a) * KNN + e];
        edist_s[a][e] = ndist[(size_t)(i0 + a) * KNN + e];
    }
    __syncthreads();

    // ---- c1: col j for atoms 4*tg .. 4*tg+3, in registers ----
    const int jc = t & 255, tg = t >> 8;
    float c1a[4];
    {
        const float b = b1[jc];
        #pragma unroll
        for (int r = 0; r < 4; ++r) c1a[r] = b;
    }
    #pragma unroll 2
    for (int k = 0; k < DIM; k += 4) {
        float w0 = w1[(size_t)(k + 0) * HD + jc];
        float wa = w1[(size_t)(k + 1) * HD + jc];
        float wb = w1[(size_t)(k + 2) * HD + jc];
        float wc = w1[(size_t)(k + 3) * HD + jc];
        #pragma unroll
        for (int r = 0; r < 4; ++r) {
            float4 c = *(const float4*)&cen_s[4 * tg + r][k];
            c1a[r] = fmaf(c.x, w0, c1a[r]);
            c1a[r] = fmaf(c.y, wa, c1a[r]);
            c1a[r] = fmaf(c.z, wb, c1a[r]);
            c1a[r] = fmaf(c.w, wc, c1a[r]);
        }
    }
    // c1 col 256: 32 lanes per atom (threads 0..255)
    if (t < 256) {
        const int a = t >> 5, l32 = t & 31;
        float p = 0.f;
        #pragma unroll
        for (int m = 0; m < 4; ++m) {
            const int k = l32 + 32 * m;
            p = fmaf(cen_s[a][k], w1[(size_t)k * HD + 256], p);
        }
        #pragma unroll
        for (int m = 1; m < 32; m <<= 1) p += __shfl_xor(p, m);
        if (l32 == 0) c1_256_s[a] = p + b1[256];
    }
    __syncthreads();

    // ---- aggregate: S[a][jc] = sum_e leaky(c1 + P[idx][jc] + d*wd) ----
    {
        const float wd = w1[(size_t)256 * HD + jc];
        float sa[4];
        #pragma unroll
        for (int r = 0; r < 4; ++r) sa[r] = 0.f;
        #pragma unroll 4
        for (int e = 0; e < KNN; ++e) {
            float pv[4];
            #pragma unroll
            for (int r = 0; r < 4; ++r)
                pv[r] = Pws[(size_t)eidx_s[4 * tg + r][e] * HD + jc];
            #pragma unroll
            for (int r = 0; r < 4; ++r)
                sa[r] += leakyf(fmaf(edist_s[4 * tg + r][e], wd, c1a[r] + pv[r]));
        }
        #pragma unroll
        for (int r = 0; r < 4; ++r) S_s[4 * tg + r][jc] = sa[r];
    }
    // col 256 (threads 0..127): a = t>>4, e = t&15
    if (t < 128) {
        const int a = t >> 4, e = t & 15;
        const float wt = w1[(size_t)256 * HD + 256];
        float h = leakyf(fmaf(edist_s[a][e], wt,
                              c1_256_s[a] + Pws[(size_t)eidx_s[a][e] * HD + 256]));
        #pragma unroll
        for (int m = 1; m < 16; m <<= 1) h += __shfl_xor(h, m);
        if (e == 0) S_s[a][256] = h;
    }
    __syncthreads();

    // ---- stage D: 2 atoms (2*tg2, 2*tg2+1) x col j ----
    const int j = t & 127, tg2 = t >> 7;            // tg2 in 0..3
    const int a0 = 2 * tg2, a1 = 2 * tg2 + 1;
    float macc0 = 16.0f * b2[j], macc1 = macc0;
    #pragma unroll 2
    for (int k = 0; k < 256; k += 4) {
        float w0 = w2[(k + 0) * DIM + j];
        float wa = w2[(k + 1) * DIM + j];
        float wb = w2[(k + 2) * DIM + j];
        float wc = w2[(k + 3) * DIM + j];
        f32x4 s0 = *(const f32x4*)&S_s[a0][k];
        f32x4 s1 = *(const f32x4*)&S_s[a1][k];
        macc0 = fmaf(s0[0], w0, macc0); macc0 = fmaf(s0[1], wa, macc0);
        macc0 = fmaf(s0[2], wb, macc0); macc0 = fmaf(s0[3], wc, macc0);
        macc1 = fmaf(s1[0], w0, macc1); macc1 = fmaf(s1[1], wa, macc1);
        macc1 = fmaf(s1[2], wb, macc1); macc1 = fmaf(s1[3], wc, macc1);
    }
    {
        const float w256 = w2[256 * DIM + j];
        macc0 = fmaf(S_s[a0][256], w256, macc0);
        macc1 = fmaf(S_s[a1][256], w256, macc1);
    }

    // GroupNorm: wave covers one 64-col group of atoms a0,a1
    const float gwj = gw[j], gbj = gb[j];
    float m0 = macc0, m1 = macc1;
    #pragma unroll
    for (int m = 1; m < 64; m <<= 1) {
        m0 += __shfl_xor(m0, m); m1 += __shfl_xor(m1, m);
    }
    const float mu0 = m0 * (1.f / 64.f), mu1 = m1 * (1.f / 64.f);
    float d0 = macc0 - mu0, d1 = macc1 - mu1;
    float v0 = d0 * d0, v1 = d1 * d1;
    #pragma unroll
    for (int m = 1; m < 64; m <<= 1) {
        v0 += __shfl_xor(v0, m); v1 += __shfl_xor(v1, m);
    }
    v0 *= (1.f / 64.f); v1 *= (1.f / 64.f);
    const float y0 = fmaf(d0 * rsqrtf(v0 + GN_EPS), gwj, gbj);
    const float y1 = fmaf(d1 * rsqrtf(v1 + GN_EPS), gwj, gbj);
    dst[(size_t)(i0 + a0) * DIM + j] = cen_s[a0][j] + leakyf(y0);
    dst[(size_t)(i0 + a1) * DIM + j] = cen_s[a1][j] + leakyf(y1);
}

extern "C" void kernel_launch(void* const* d_in, const int* in_sizes, int n_in,
                              void* d_out, int out_size, void* d_ws, size_t ws_size,
                              hipStream_t stream)
{
    const size_t out_bytes = (size_t)out_size * sizeof(float);
    if (n_in != 21) { (void)hipMemsetAsync(d_out, 0x43, out_bytes, stream); return; }

    const size_t n_atoms_f = (size_t)NAT * DIM;
    const size_t n_emb_f   = (size_t)NXQ * DIM;
    const size_t n_P_f     = (size_t)NAT * HD;
    const size_t floats_needed = n_atoms_f * 2 + n_emb_f
        + (size_t)NAT * KNN * 2 + (size_t)NXQ * KNN * 2 + n_P_f + 16;
    if (ws_size < floats_needed * 4 + 64) {
        (void)hipMemsetAsync(d_out, 0x41, out_bytes, stream);
        return;
    }

    const float* xyz    = (const float*)d_in[0];
    const float* axyz   = (const float*)d_in[1];
    const float* af     = (const float*)d_in[2];
    const int*   xbatch = (const int*)d_in[3];
    const int*   abatch = (const int*)d_in[4];
    const float* tw1    = (const float*)d_in[5];
    const float* tb1    = (const float*)d_in[6];
    const float* tw2    = (const float*)d_in[7];
    const float* tb2    = (const float*)d_in[8];
    const float* aa_w1  = (const float*)d_in[9];
    const float* aa_b1  = (const float*)d_in[10];
    const float* aa_w2  = (const float*)d_in[11];
    const float* aa_b2  = (const float*)d_in[12];
    const float* aa_gw  = (const float*)d_in[13];
    const float* aa_gb  = (const float*)d_in[14];
    const float* ae_w1  = (const float*)d_in[15];
    const float* ae_b1  = (const float*)d_in[16];
    const float* ae_w2  = (const float*)d_in[17];
    const float* ae_b2  = (const float*)d_in[18];
    const float* ae_gw  = (const float*)d_in[19];
    const float* ae_gb  = (const float*)d_in[20];

    float* fp      = (float*)d_ws;
    float* atoms_a = fp;                 fp += n_atoms_f;
    float* atoms_b = fp;                 fp += n_atoms_f;
    float* emb     = fp;                 fp += n_emb_f;
    int*   idx_aa  = (int*)fp;           fp += (size_t)NAT * KNN;
    float* dist_aa = fp;                 fp += (size_t)NAT * KNN;
    int*   idx_xa  = (int*)fp;           fp += (size_t)NXQ * KNN;
    float* dist_xa = fp;                 fp += (size_t)NXQ * KNN;
    float* Pws     = fp;                 fp += n_P_f;
    int*   bstarts = (int*)fp;           fp += 16;

    const int NOUT = NXQ * DIM;

    fill_f32_r11<<<(NOUT + 255) / 256, 256, 0, stream>>>(emb, NOUT, 1.0f);
    feat_transform_r11<<<NAT, 128, 0, stream>>>(af, tw1, tb1, tw2, tb2, atoms_a);
    batch_starts_r11<<<1, 64, 0, stream>>>(abatch, bstarts);
    knn_r11<<<(NAT + NXQ + 3) / 4, 256, 0, stream>>>(
        xyz, xbatch, axyz, abatch, bstarts, idx_aa, dist_aa, idx_xa, dist_xa);

    // ---- atom-atom layers ----
    float* cur = atoms_a;
    float* nxt = atoms_b;
    for (int i = 0; i < NLAYER; ++i) {
        const float* w1p = aa_w1 + (size_t)i * HD * HD;
        lin128_r11<<<NAT / 8, 512, 0, stream>>>(cur, w1p, Pws);
        layer_fused_r11<<<NAT / 8, 512, 0, stream>>>(
            cur, Pws, idx_aa, dist_aa,
            w1p, aa_b1 + (size_t)i * HD,
            aa_w2 + (size_t)i * HD * DIM, aa_b2 + (size_t)i * DIM,
            aa_gw + (size_t)i * DIM, aa_gb + (size_t)i * DIM, nxt);
        float* tmp = cur; cur = nxt; nxt = tmp;
    }
    const float* atoms_final = cur;

    // ---- xyz-atom layers (emb updated in place; last layer writes d_out) ----
    for (int i = 0; i < NLAYER; ++i) {
        const float* w1p = ae_w1 + (size_t)i * HD * HD;
        lin128_r11<<<NAT / 8, 512, 0, stream>>>(atoms_final, w1p, Pws);
        float* dsti = (i == NLAYER - 1) ? (float*)d_out : emb;
        layer_fused_r11<<<NXQ / 8, 512, 0, stream>>>(
            emb, Pws, idx_xa, dist_xa,
            w1p, ae_b1 + (size_t)i * HD,
            ae_w2 + (size_t)i * HD * DIM, ae_b2 + (size_t)i * DIM,
            ae_gw + (size_t)i * DIM, ae_gb + (size_t)i * DIM, dsti);
    }
}